// Round 4
// baseline (3730.986 us; speedup 1.0000x reference)
//
#include <hip/hip_runtime.h>
#include <math.h>

// MambaNet forward: stem (conv/BN/relu) -> 6x [LN -> Mamba -> LN -> MLP] -> pool -> fc
// All f32. T = 18432 tokens (B=2, L=9216), d_model=64, d_inner=128, N_state=16.

#define TTOK 18432
#define LSEQ 9216
#define BSZ 2
#define CS 96     // scan chunk size
#define NCH 96    // number of chunks (CS*NCH == LSEQ)

__device__ __forceinline__ float sigmoidf_(float x){ return 1.f/(1.f+expf(-x)); }

// ---------------- Stem ----------------
__global__ __launch_bounds__(256) void k_stem_conv1(const float* __restrict__ x,
    const float* __restrict__ w1, const float* __restrict__ scw,
    float* __restrict__ c1, float* __restrict__ res){
  int idx = blockIdx.x*256 + threadIdx.x;
  if (idx >= BSZ*64*9216) return;
  int hw = idx % 9216; int c = (idx/9216) & 63; int b = idx/(9216*64);
  int h = hw/96, w = hw%96;
  const float* xb = x + b*9216;
  float acc = 0.f;
  for (int dh=-1; dh<=1; ++dh){
    int hh=h+dh; if(hh<0||hh>=96) continue;
    for (int dw=-1; dw<=1; ++dw){
      int ww=w+dw; if(ww<0||ww>=96) continue;
      acc += xb[hh*96+ww]*w1[c*9+(dh+1)*3+(dw+1)];
    }
  }
  c1[idx]=acc;
  res[idx]=xb[hw]*scw[c];
}

// per-channel batch stats for TWO tensors in one launch (128 blocks)
__global__ __launch_bounds__(256) void k_bnstats2(const float* __restrict__ srcA,
    const float* __restrict__ srcB,
    float* __restrict__ meanA, float* __restrict__ istdA,
    float* __restrict__ meanB, float* __restrict__ istdB){
  int c = blockIdx.x & 63; int tid = threadIdx.x;
  const float* src = (blockIdx.x < 64)? srcA : srcB;
  float* mean = (blockIdx.x < 64)? meanA : meanB;
  float* istd = (blockIdx.x < 64)? istdA : istdB;
  float s=0.f, s2=0.f;
  for (int b=0;b<BSZ;++b){
    const float* p = src + (size_t)(b*64+c)*9216;
    for (int i=tid;i<9216;i+=256){ float v=p[i]; s+=v; s2+=v*v; }
  }
  __shared__ float ls[256], ls2[256];
  ls[tid]=s; ls2[tid]=s2; __syncthreads();
  for(int off=128;off>0;off>>=1){
    if(tid<off){ ls[tid]+=ls[tid+off]; ls2[tid]+=ls2[tid+off]; }
    __syncthreads();
  }
  if(tid==0){
    float m=ls[0]/18432.f; float v=ls2[0]/18432.f - m*m;
    mean[c]=m; istd[c]=rsqrtf(v+1e-5f);
  }
}

__global__ __launch_bounds__(256) void k_bnstats(const float* __restrict__ src,
    float* __restrict__ mean, float* __restrict__ istd){
  int c = blockIdx.x; int tid = threadIdx.x;
  float s=0.f, s2=0.f;
  for (int b=0;b<BSZ;++b){
    const float* p = src + (size_t)(b*64+c)*9216;
    for (int i=tid;i<9216;i+=256){ float v=p[i]; s+=v; s2+=v*v; }
  }
  __shared__ float ls[256], ls2[256];
  ls[tid]=s; ls2[tid]=s2; __syncthreads();
  for(int off=128;off>0;off>>=1){
    if(tid<off){ ls[tid]+=ls[tid+off]; ls2[tid]+=ls2[tid+off]; }
    __syncthreads();
  }
  if(tid==0){
    float m=ls[0]/18432.f; float v=ls2[0]/18432.f - m*m;
    mean[c]=m; istd[c]=rsqrtf(v+1e-5f);
  }
}

__global__ __launch_bounds__(256) void k_bnrelu(float* __restrict__ t,
    const float* __restrict__ mean, const float* __restrict__ istd,
    const float* __restrict__ g, const float* __restrict__ bb){
  int idx = blockIdx.x*256+threadIdx.x; if(idx>=BSZ*64*9216) return;
  int c=(idx/9216)&63;
  float v=(t[idx]-mean[c])*istd[c]*g[c]+bb[c];
  t[idx]=fmaxf(v,0.f);
}

// Tiled direct conv 64->64, 3x3. Block = (b, out-row h, half-row wh).
__global__ __launch_bounds__(256) void k_stem_conv2(const float* __restrict__ h1,
    const float* __restrict__ w2, float* __restrict__ c2){
  __shared__ __align__(16) float in_lds[16*156];   // [ci][3][52]
  __shared__ float w_lds[64*145];                  // [co][16*9 (+1 pad)]
  int blk=blockIdx.x;
  int wh=blk&1, h=(blk>>1)%96, b=blk/(2*96);
  int tid=threadIdx.x;
  int co=tid&63, pg=tid>>6;
  float acc[12];
  #pragma unroll
  for(int i=0;i<12;++i) acc[i]=0.f;
  int wbase = wh*48;
  const float* hb = h1 + (size_t)b*64*9216;
  for(int cc=0;cc<4;++cc){
    __syncthreads();
    for(int e=tid;e<16*3*50;e+=256){
      int ci=e/150, rr=e%150; int tr=rr/50, wl=rr%50;
      int hh=h+tr-1, ww=wbase+wl-1;
      float v=0.f;
      if(hh>=0&&hh<96&&ww>=0&&ww<96) v=hb[(size_t)(cc*16+ci)*9216 + hh*96+ww];
      in_lds[ci*156 + tr*52 + wl]=v;
    }
    for(int e=tid;e<64*144;e+=256){
      int c_=e/144, r=e%144;
      w_lds[c_*145+r]=w2[(size_t)c_*576 + cc*144 + r];
    }
    __syncthreads();
    for(int ci=0;ci<16;++ci){
      float wr[9];
      #pragma unroll
      for(int t=0;t<9;++t) wr[t]=w_lds[co*145+ci*9+t];
      const float* ibase = in_lds + ci*156;
      #pragma unroll
      for(int tr=0;tr<3;++tr){
        const float* row = ibase + tr*52 + pg*12;
        float win[14];
        #pragma unroll
        for(int q=0;q<14;++q) win[q]=row[q];
        #pragma unroll
        for(int p=0;p<12;++p)
          acc[p] += win[p]*wr[tr*3+0] + win[p+1]*wr[tr*3+1] + win[p+2]*wr[tr*3+2];
      }
    }
  }
  size_t obase=(size_t)(b*64+co)*9216 + h*96 + wbase + pg*12;
  #pragma unroll
  for(int p=0;p<3;++p)
    *reinterpret_cast<float4*>(&c2[obase+p*4]) = *reinterpret_cast<float4*>(&acc[p*4]);
}

// merge: h[b,hw,c] = relu(bn2(c2) + bn_sc(res))  (NCHW -> token-major channel-last)
__global__ __launch_bounds__(256) void k_stem_merge(const float* __restrict__ c2,
    const float* __restrict__ res,
    const float* __restrict__ m2,const float* __restrict__ i2,
    const float* __restrict__ g2,const float* __restrict__ b2,
    const float* __restrict__ ms,const float* __restrict__ is,
    const float* __restrict__ gs,const float* __restrict__ bs,
    float* __restrict__ hOut){
  int idx=blockIdx.x*256+threadIdx.x; if(idx>=BSZ*64*9216)return;
  int c=idx&63; int hw=(idx>>6)%9216; int b=idx/(64*9216);
  size_t src=(size_t)(b*64+c)*9216+hw;
  float v=(c2[src]-m2[c])*i2[c]*g2[c]+b2[c];
  float r=(res[src]-ms[c])*is[c]*gs[c]+bs[c];
  hOut[idx]=fmaxf(v+r,0.f);
}

// ---------------- fused LayerNorm + GEMM (N=256, K=64), register-resident W ----
// Thread j=tid owns output column j: W[j][0..63] in 64 VGPRs. LDS = LN'd A tile
// only (broadcast reads, conflict-free). 32 tokens/block, grid 576 (exact).
template<int OP>
__global__ __launch_bounds__(256,2) void k_ln_gemm(
    const float* __restrict__ A, const float* __restrict__ lng, const float* __restrict__ lnb,
    const float* __restrict__ W, const float* __restrict__ bias,
    float* __restrict__ out){
  __shared__ __align__(16) float Al[32*64];
  int tid = threadIdx.x;
  int j = tid;
  float wreg[64];
  #pragma unroll
  for(int k4=0;k4<64;k4+=4){
    float4 w4 = *reinterpret_cast<const float4*>(&W[(size_t)j*64+k4]);
    wreg[k4]=w4.x; wreg[k4+1]=w4.y; wreg[k4+2]=w4.z; wreg[k4+3]=w4.w;
  }
  float bv = (OP==1)? bias[j] : 0.f;
  float gg = lng[tid&63], bbv = lnb[tid&63];
  int t0 = blockIdx.x*32;
  // LN: 32 rows, 4 rows per pass (one token per wave), 8 passes
  #pragma unroll
  for(int p=0;p<8;++p){
    int r = p*4 + (tid>>6);
    int c = tid&63;
    float v = A[(size_t)(t0+r)*64+c];
    float s=v, s2=v*v;
    #pragma unroll
    for(int off=32;off>0;off>>=1){ s+=__shfl_xor(s,off); s2+=__shfl_xor(s2,off); }
    float m=s*(1.f/64.f), var=s2*(1.f/64.f)-m*m;
    Al[r*64+c] = (v-m)*rsqrtf(var+1e-5f)*gg + bbv;
  }
  __syncthreads();
  #pragma unroll
  for(int g=0;g<4;++g){
    float acc[8];
    #pragma unroll
    for(int r=0;r<8;++r) acc[r]=bv;
    #pragma unroll
    for(int k4=0;k4<64;k4+=4){
      #pragma unroll
      for(int r=0;r<8;++r){
        float4 a = *reinterpret_cast<const float4*>(&Al[(g*8+r)*64 + k4]);
        acc[r] += a.x*wreg[k4] + a.y*wreg[k4+1] + a.z*wreg[k4+2] + a.w*wreg[k4+3];
      }
    }
    #pragma unroll
    for(int r=0;r<8;++r){
      int t = t0 + g*8 + r;
      float v = acc[r];
      if(OP==1) v = 0.5f*v*(1.f+erff(v*0.70710678118f));
      out[(size_t)t*256+j] = v;
    }
  }
}

// ---------------- GEMM N=64 (K=128/256), reg-W k-split + residual (+bias) ----
// Thread (j=tid&63, q=tid>>6) holds W[j][q*KQ .. q*KQ+KQ-1] in regs; A read
// directly from global with wave-uniform addresses (q hoisted to SGPR via
// readfirstlane -> scalar loads). LDS only for the 4-way k-group reduction.
// 48 tokens/block, grid 384 (exact; no duplicate coverage -> res-add safe).
template<int K>
__global__ __launch_bounds__(256,2) void k_gemm64(
    const float* __restrict__ A, const float* __restrict__ W,
    const float* __restrict__ bias, const float* __restrict__ res,
    float* __restrict__ out){
  constexpr int KQ = K/4;
  __shared__ float Pl[4*8*64];
  int tid = threadIdx.x;
  int j = tid & 63;
  int qu = __builtin_amdgcn_readfirstlane(tid>>6);
  float wreg[KQ];
  const float* wp = W + (size_t)j*K + qu*KQ;
  #pragma unroll
  for(int k4=0;k4<KQ;k4+=4){
    float4 w4 = *reinterpret_cast<const float4*>(wp + k4);
    wreg[k4]=w4.x; wreg[k4+1]=w4.y; wreg[k4+2]=w4.z; wreg[k4+3]=w4.w;
  }
  int t0 = blockIdx.x*48;
  for(int g=0; g<6; ++g){
    int tb = t0 + g*8;
    float acc[8];
    #pragma unroll
    for(int r=0;r<8;++r) acc[r]=0.f;
    const float* ap = A + (size_t)tb*K + qu*KQ;
    #pragma unroll
    for(int k4=0;k4<KQ;k4+=4){
      #pragma unroll
      for(int r=0;r<8;++r){
        float4 a = *reinterpret_cast<const float4*>(ap + (size_t)r*K + k4);
        acc[r] += a.x*wreg[k4] + a.y*wreg[k4+1] + a.z*wreg[k4+2] + a.w*wreg[k4+3];
      }
    }
    if(g) __syncthreads();           // prior Pl readers done before overwrite
    #pragma unroll
    for(int r=0;r<8;++r) Pl[(qu*8+r)*64 + j] = acc[r];
    __syncthreads();
    #pragma unroll
    for(int o=0;o<2;++o){
      int idx = o*256 + tid; int r = idx>>6, jj = idx&63; int t = tb + r;
      float v = Pl[r*64+jj] + Pl[512+r*64+jj] + Pl[1024+r*64+jj] + Pl[1536+r*64+jj];
      if(bias) v += bias[jj];
      v += res[(size_t)t*64+jj];
      out[(size_t)t*64+jj] = v;
    }
  }
}

// ---------------- depthwise causal conv (k=4) + silu ----------------
__global__ __launch_bounds__(256) void k_dwconv(const float* __restrict__ xz,
    const float* __restrict__ cw, const float* __restrict__ cb, float* __restrict__ xc){
  int idx=blockIdx.x*256+threadIdx.x; if(idx>=TTOK*128)return;
  int d=idx&127; int t=idx>>7;
  int b=t/LSEQ, l=t%LSEQ;
  float acc=cb[d];
  #pragma unroll
  for(int k=0;k<4;++k){
    int ls=l-3+k;
    if(ls>=0) acc += cw[d*4+k]*xz[(size_t)(b*LSEQ+ls)*256 + d];
  }
  xc[idx]=acc*sigmoidf_(acc);
}

// ---------------- x_proj GEMM (N=36,K=128) + fused delta ----------------
__global__ __launch_bounds__(256,2) void k_xproj_delta(
    const float* __restrict__ A, const float* __restrict__ W,
    const float* __restrict__ dtw, const float* __restrict__ dtb,
    float* __restrict__ dbl, float* __restrict__ delta, int tokensPerBlock){
  __shared__ __align__(16) float lds[37*128 + 56*128 + 56*4 + 512 + 128];
  float* Wl  = lds;               // [128][37] (pad 36->37: conflict-free)
  float* Al  = Wl + 37*128;       // [56][128]
  float* dtv = Al + 56*128;       // [56][4]
  float* dtwl= dtv + 56*4;        // [128][4]
  float* dtbl= dtwl + 512;        // [128]
  int tid=threadIdx.x;
  for(int i=tid;i<36*128;i+=256){int jj=i/128,kk=i%128; Wl[kk*37+jj]=W[i];}
  for(int i=tid;i<512;i+=256) dtwl[i]=dtw[i];
  if(tid<128) dtbl[tid]=dtb[tid];
  int j=tid%36, tg=tid/36;
  bool active = tg<7;
  int tStart=blockIdx.x*tokensPerBlock;
  for(int t0=tStart;t0<tStart+tokensPerBlock;t0+=56){
    __syncthreads();
    for(int i=tid;i<56*128;i+=256){
      int r=i>>7, kk=i&127; int t=t0+r;
      Al[i]=(t<TTOK)?A[(size_t)t*128+kk]:0.f;
    }
    __syncthreads();
    if(active){
      float acc[8];
      #pragma unroll
      for(int i=0;i<8;++i) acc[i]=0.f;
      const float* ar=Al+tg*8*128;
      for(int k=0;k<128;k+=4){
        float w0=Wl[k*37+j],w1=Wl[(k+1)*37+j],w2=Wl[(k+2)*37+j],w3=Wl[(k+3)*37+j];
        #pragma unroll
        for(int i=0;i<8;++i){
          float4 a=*reinterpret_cast<const float4*>(ar+i*128+k);
          acc[i]+=a.x*w0+a.y*w1+a.z*w2+a.w*w3;
        }
      }
      #pragma unroll
      for(int i=0;i<8;++i){
        int t=t0+tg*8+i;
        if(t<TTOK){
          dbl[(size_t)t*36+j]=acc[i];
          if(j<4) dtv[(tg*8+i)*4+j]=acc[i];
        }
      }
    }
    __syncthreads();
    for(int e=tid;e<56*128;e+=256){
      int r=e>>7, d=e&127; int t=t0+r;
      if(t<TTOK){
        float a0=dtv[r*4+0]*dtwl[d*4+0]+dtv[r*4+1]*dtwl[d*4+1]
                +dtv[r*4+2]*dtwl[d*4+2]+dtv[r*4+3]*dtwl[d*4+3]+dtbl[d];
        delta[(size_t)t*128+d]=fmaxf(a0,0.f)+log1pf(expf(-fabsf(a0)));
      }
    }
  }
}

// ---------------- scan phase 1 ----------------
__global__ __launch_bounds__(256) void k_scan1(const float* __restrict__ delta,
    const float* __restrict__ xc, const float* __restrict__ dbl,
    const float* __restrict__ A_log, float* __restrict__ chA, float* __restrict__ chH){
  int idx=blockIdx.x*256+threadIdx.x;
  int n=idx&15; int d=(idx>>4)&127; int chunk=(idx>>11)%NCH; int b=(idx>>11)/NCH;
  float a_const = -expf(A_log[d*16+n]);
  float aprod=1.f, h=0.f;
  int tBase = b*LSEQ + chunk*CS;
  for(int i=0;i<CS;++i){
    int t=tBase+i;
    float dl=delta[(size_t)t*128+d];
    float xv=xc[(size_t)t*128+d];
    float Bv=dbl[(size_t)t*36+4+n];
    float da=expf(dl*a_const);
    h = da*h + dl*xv*Bv;
    aprod *= da;
  }
  chA[idx]=aprod; chH[idx]=h;
}

// ---------------- scan phase 2 ----------------
__global__ __launch_bounds__(256) void k_scan2(const float* __restrict__ chA,
    const float* __restrict__ chH, float* __restrict__ chIn){
  int idx=blockIdx.x*256+threadIdx.x; if(idx>=BSZ*2048) return;
  int b=idx>>11; int dn=idx&2047;
  float H=0.f;
  for(int c=0;c<NCH;++c){
    size_t o=(size_t)(b*NCH+c)*2048+dn;
    chIn[o]=H;
    H = chA[o]*H + chH[o];
  }
}

// ---------------- scan phase 3 + fused gate ----------------
__global__ __launch_bounds__(256) void k_scan3(const float* __restrict__ delta,
    const float* __restrict__ xc, const float* __restrict__ dbl,
    const float* __restrict__ A_log, const float* __restrict__ chIn,
    const float* __restrict__ xz, const float* __restrict__ Dp,
    float* __restrict__ y){
  int tid=threadIdx.x;
  int gid = blockIdx.x*16 + (tid>>4);
  int n = tid&15;
  int d = gid%128; int chunk=(gid/128)%NCH; int b=gid/(128*NCH);
  float a_const = -expf(A_log[d*16+n]);
  float dpv = Dp[d];
  float h = chIn[(size_t)(b*NCH+chunk)*2048 + d*16+n];
  int tBase=b*LSEQ+chunk*CS;
  for(int i=0;i<CS;++i){
    int t=tBase+i;
    float dl=delta[(size_t)t*128+d];
    float xv=xc[(size_t)t*128+d];
    float Bv=dbl[(size_t)t*36+4+n];
    float Cv=dbl[(size_t)t*36+20+n];
    float da=expf(dl*a_const);
    h=da*h+dl*xv*Bv;
    float contrib=h*Cv;
    contrib += __shfl_xor(contrib,1);
    contrib += __shfl_xor(contrib,2);
    contrib += __shfl_xor(contrib,4);
    contrib += __shfl_xor(contrib,8);
    if(n==0){
      float z=xz[(size_t)t*256+128+d];
      y[(size_t)t*128+d]=(contrib + xv*dpv)*(z*sigmoidf_(z));
    }
  }
}

// ---------------- pool stage 1: 256 blocks of partials ----------------
__global__ __launch_bounds__(256) void k_pool1(const float* __restrict__ h,
    float* __restrict__ partial){
  int blk=blockIdx.x;            // b = blk>>7, slice s = blk&127 (72 px each)
  int b=blk>>7, s=blk&127;
  int tid=threadIdx.x; int c=tid&63, sl=tid>>6;
  float sum=0.f;
  int base = s*72;
  for(int p=sl;p<72;p+=4) sum += h[((size_t)b*9216 + base+p)*64 + c];
  __shared__ float ls[256];
  ls[tid]=sum; __syncthreads();
  if(sl==0) partial[(size_t)blk*64+c] = ls[c]+ls[64+c]+ls[128+c]+ls[192+c];
}

// ---------------- pool stage 2 + fc ----------------
__global__ __launch_bounds__(128) void k_pool2(const float* __restrict__ partial,
    const float* __restrict__ fcw, const float* __restrict__ fcb, float* __restrict__ out){
  int tid=threadIdx.x; int b=tid>>6, c=tid&63;
  float s=0.f;
  for(int k=0;k<128;++k) s += partial[(size_t)(b*128+k)*64+c];
  float v=(s/9216.f)*fcw[c];
  #pragma unroll
  for(int off=32;off>0;off>>=1) v+=__shfl_xor(v,off);
  if(c==0) out[b]=v+fcb[0];
}

extern "C" void kernel_launch(void* const* d_in, const int* in_sizes, int n_in,
                              void* d_out, int out_size, void* d_ws, size_t ws_size,
                              hipStream_t stream) {
  const float* x       = (const float*)d_in[0];
  const float* conv1_w = (const float*)d_in[1];
  const float* bn1_g   = (const float*)d_in[2];
  const float* bn1_b   = (const float*)d_in[3];
  const float* conv2_w = (const float*)d_in[4];
  const float* bn2_g   = (const float*)d_in[5];
  const float* bn2_b   = (const float*)d_in[6];
  const float* sc_w    = (const float*)d_in[7];
  const float* sc_g    = (const float*)d_in[8];
  const float* sc_b    = (const float*)d_in[9];
  const float* ln1_g   = (const float*)d_in[10];
  const float* ln1_b   = (const float*)d_in[11];
  const float* in_proj_w = (const float*)d_in[12];
  const float* conv_w  = (const float*)d_in[13];
  const float* conv_b  = (const float*)d_in[14];
  const float* x_proj_w= (const float*)d_in[15];
  const float* dt_w    = (const float*)d_in[16];
  const float* dt_b    = (const float*)d_in[17];
  const float* A_log   = (const float*)d_in[18];
  const float* Dp      = (const float*)d_in[19];
  const float* out_proj_w = (const float*)d_in[20];
  const float* ln2_g   = (const float*)d_in[21];
  const float* ln2_b   = (const float*)d_in[22];
  const float* mlp_w1  = (const float*)d_in[23];
  const float* mlp_b1  = (const float*)d_in[24];
  const float* mlp_w2  = (const float*)d_in[25];
  const float* mlp_b2  = (const float*)d_in[26];
  const float* fc_w    = (const float*)d_in[27];
  const float* fc_b    = (const float*)d_in[28];

  const size_t T = TTOK;
  float* ws    = (float*)d_ws;
  float* bufH  = ws;                  // T*64
  float* bufXZ = bufH  + 64*T;        // T*256 (also stem scratch)
  float* bufXC = bufXZ + 256*T;       // T*128
  float* bufDBL= bufXC + 128*T;       // T*36
  float* bufDLT= bufDBL+ 36*T;        // T*128
  float* bufY  = bufDLT+ 128*T;       // T*128
  float* chA   = bufY  + 128*T;       // B*NCH*2048
  float* chH   = chA   + BSZ*NCH*2048;
  float* chIn  = chH   + BSZ*NCH*2048;
  float* stats = chIn  + BSZ*NCH*2048; // 6*64
  float* partial = stats + 6*64;       // 256*64

  // stem scratch aliases inside bufXZ (each 2*64*9216 = 1179648 floats)
  float* c1   = bufXZ;
  float* c2   = bufXZ + 1179648;
  float* resb = bufXZ + 2*1179648;
  float *m1=stats, *i1=stats+64, *m2=stats+128, *i2=stats+192, *ms=stats+256, *is=stats+320;

  const int NE = BSZ*64*9216;
  const int gE = (NE+255)/256;

  k_stem_conv1<<<gE,256,0,stream>>>(x, conv1_w, sc_w, c1, resb);
  k_bnstats2<<<128,256,0,stream>>>(c1, resb, m1, i1, ms, is);
  k_bnrelu<<<gE,256,0,stream>>>(c1, m1, i1, bn1_g, bn1_b);
  k_stem_conv2<<<BSZ*96*2,256,0,stream>>>(c1, conv2_w, c2);
  k_bnstats<<<64,256,0,stream>>>(c2, m2, i2);
  k_stem_merge<<<gE,256,0,stream>>>(c2, resb, m2, i2, bn2_g, bn2_b, ms, is, sc_g, sc_b, bufH);

  const int gD = (int)((T*128+255)/256);
  for (int i=0;i<6;++i){
    const float* inw  = in_proj_w + (size_t)i*256*64;
    const float* cw   = conv_w    + (size_t)i*128*4;
    const float* cb   = conv_b    + (size_t)i*128;
    const float* xpw  = x_proj_w  + (size_t)i*36*128;
    const float* dtw  = dt_w      + (size_t)i*128*4;
    const float* dtb  = dt_b      + (size_t)i*128;
    const float* alog = A_log     + (size_t)i*128*16;
    const float* dp   = Dp        + (size_t)i*128;
    const float* opw  = out_proj_w+ (size_t)i*64*128;
    const float* w1   = mlp_w1    + (size_t)i*256*64;
    const float* b1   = mlp_b1    + (size_t)i*256;
    const float* w2   = mlp_w2    + (size_t)i*64*256;
    const float* b2   = mlp_b2    + (size_t)i*64;

    k_ln_gemm<0><<<576,256,0,stream>>>(bufH, ln1_g+i*64, ln1_b+i*64, inw, nullptr, bufXZ);
    k_dwconv<<<gD,256,0,stream>>>(bufXZ, cw, cb, bufXC);
    k_xproj_delta<<<330,256,0,stream>>>(bufXC, xpw, dtw, dtb, bufDBL, bufDLT, 56);
    k_scan1<<<BSZ*NCH*2048/256,256,0,stream>>>(bufDLT, bufXC, bufDBL, alog, chA, chH);
    k_scan2<<<(BSZ*2048+255)/256,256,0,stream>>>(chA, chH, chIn);
    k_scan3<<<BSZ*NCH*128/16,256,0,stream>>>(bufDLT, bufXC, bufDBL, alog, chIn, bufXZ, dp, bufY);
    k_gemm64<128><<<384,256,0,stream>>>(bufY, opw, nullptr, bufH, bufH);
    k_ln_gemm<1><<<576,256,0,stream>>>(bufH, ln2_g+i*64, ln2_b+i*64, w1, b1, bufXZ);
    k_gemm64<256><<<384,256,0,stream>>>(bufXZ, w2, b2, bufH, bufH);
  }

  k_pool1<<<256,256,0,stream>>>(bufH, partial);
  k_pool2<<<1,128,0,stream>>>(partial, fc_w, fc_b, (float*)d_out);
}

// Round 6
// 2432.129 us; speedup vs baseline: 1.5340x; 1.5340x over previous
//
#include <hip/hip_runtime.h>
#include <math.h>

// MambaNet forward: stem (conv/BN/relu) -> 6x [LN -> Mamba -> LN -> MLP] -> pool -> fc
// All f32. T = 18432 tokens (B=2, L=9216), d_model=64, d_inner=128, N_state=16.

#define TTOK 18432
#define LSEQ 9216
#define BSZ 2
#define CS 96     // scan chunk size
#define NCH 96    // number of chunks (CS*NCH == LSEQ)

__device__ __forceinline__ float sigmoidf_(float x){ return 1.f/(1.f+expf(-x)); }

// ---------------- Stem ----------------
__global__ __launch_bounds__(256) void k_stem_conv1(const float* __restrict__ x,
    const float* __restrict__ w1, const float* __restrict__ scw,
    float* __restrict__ c1, float* __restrict__ res){
  int idx = blockIdx.x*256 + threadIdx.x;
  if (idx >= BSZ*64*9216) return;
  int hw = idx % 9216; int c = (idx/9216) & 63; int b = idx/(9216*64);
  int h = hw/96, w = hw%96;
  const float* xb = x + b*9216;
  float acc = 0.f;
  for (int dh=-1; dh<=1; ++dh){
    int hh=h+dh; if(hh<0||hh>=96) continue;
    for (int dw=-1; dw<=1; ++dw){
      int ww=w+dw; if(ww<0||ww>=96) continue;
      acc += xb[hh*96+ww]*w1[c*9+(dh+1)*3+(dw+1)];
    }
  }
  c1[idx]=acc;
  res[idx]=xb[hw]*scw[c];
}

// per-channel batch stats for TWO tensors in one launch (128 blocks)
__global__ __launch_bounds__(256) void k_bnstats2(const float* __restrict__ srcA,
    const float* __restrict__ srcB,
    float* __restrict__ meanA, float* __restrict__ istdA,
    float* __restrict__ meanB, float* __restrict__ istdB){
  int c = blockIdx.x & 63; int tid = threadIdx.x;
  const float* src = (blockIdx.x < 64)? srcA : srcB;
  float* mean = (blockIdx.x < 64)? meanA : meanB;
  float* istd = (blockIdx.x < 64)? istdA : istdB;
  float s=0.f, s2=0.f;
  for (int b=0;b<BSZ;++b){
    const float* p = src + (size_t)(b*64+c)*9216;
    for (int i=tid;i<9216;i+=256){ float v=p[i]; s+=v; s2+=v*v; }
  }
  __shared__ float ls[256], ls2[256];
  ls[tid]=s; ls2[tid]=s2; __syncthreads();
  for(int off=128;off>0;off>>=1){
    if(tid<off){ ls[tid]+=ls[tid+off]; ls2[tid]+=ls2[tid+off]; }
    __syncthreads();
  }
  if(tid==0){
    float m=ls[0]/18432.f; float v=ls2[0]/18432.f - m*m;
    mean[c]=m; istd[c]=rsqrtf(v+1e-5f);
  }
}

__global__ __launch_bounds__(256) void k_bnstats(const float* __restrict__ src,
    float* __restrict__ mean, float* __restrict__ istd){
  int c = blockIdx.x; int tid = threadIdx.x;
  float s=0.f, s2=0.f;
  for (int b=0;b<BSZ;++b){
    const float* p = src + (size_t)(b*64+c)*9216;
    for (int i=tid;i<9216;i+=256){ float v=p[i]; s+=v; s2+=v*v; }
  }
  __shared__ float ls[256], ls2[256];
  ls[tid]=s; ls2[tid]=s2; __syncthreads();
  for(int off=128;off>0;off>>=1){
    if(tid<off){ ls[tid]+=ls[tid+off]; ls2[tid]+=ls2[tid+off]; }
    __syncthreads();
  }
  if(tid==0){
    float m=ls[0]/18432.f; float v=ls2[0]/18432.f - m*m;
    mean[c]=m; istd[c]=rsqrtf(v+1e-5f);
  }
}

__global__ __launch_bounds__(256) void k_bnrelu(float* __restrict__ t,
    const float* __restrict__ mean, const float* __restrict__ istd,
    const float* __restrict__ g, const float* __restrict__ bb){
  int idx = blockIdx.x*256+threadIdx.x; if(idx>=BSZ*64*9216) return;
  int c=(idx/9216)&63;
  float v=(t[idx]-mean[c])*istd[c]*g[c]+bb[c];
  t[idx]=fmaxf(v,0.f);
}

// Tiled direct conv 64->64, 3x3. Block = (b, out-row h, half-row wh).
__global__ __launch_bounds__(256) void k_stem_conv2(const float* __restrict__ h1,
    const float* __restrict__ w2, float* __restrict__ c2){
  __shared__ __align__(16) float in_lds[16*156];   // [ci][3][52]
  __shared__ float w_lds[64*145];                  // [co][16*9 (+1 pad)]
  int blk=blockIdx.x;
  int wh=blk&1, h=(blk>>1)%96, b=blk/(2*96);
  int tid=threadIdx.x;
  int co=tid&63, pg=tid>>6;
  float acc[12];
  #pragma unroll
  for(int i=0;i<12;++i) acc[i]=0.f;
  int wbase = wh*48;
  const float* hb = h1 + (size_t)b*64*9216;
  for(int cc=0;cc<4;++cc){
    __syncthreads();
    for(int e=tid;e<16*3*50;e+=256){
      int ci=e/150, rr=e%150; int tr=rr/50, wl=rr%50;
      int hh=h+tr-1, ww=wbase+wl-1;
      float v=0.f;
      if(hh>=0&&hh<96&&ww>=0&&ww<96) v=hb[(size_t)(cc*16+ci)*9216 + hh*96+ww];
      in_lds[ci*156 + tr*52 + wl]=v;
    }
    for(int e=tid;e<64*144;e+=256){
      int c_=e/144, r=e%144;
      w_lds[c_*145+r]=w2[(size_t)c_*576 + cc*144 + r];
    }
    __syncthreads();
    for(int ci=0;ci<16;++ci){
      float wr[9];
      #pragma unroll
      for(int t=0;t<9;++t) wr[t]=w_lds[co*145+ci*9+t];
      const float* ibase = in_lds + ci*156;
      #pragma unroll
      for(int tr=0;tr<3;++tr){
        const float* row = ibase + tr*52 + pg*12;
        float win[14];
        #pragma unroll
        for(int q=0;q<14;++q) win[q]=row[q];
        #pragma unroll
        for(int p=0;p<12;++p)
          acc[p] += win[p]*wr[tr*3+0] + win[p+1]*wr[tr*3+1] + win[p+2]*wr[tr*3+2];
      }
    }
  }
  size_t obase=(size_t)(b*64+co)*9216 + h*96 + wbase + pg*12;
  #pragma unroll
  for(int p=0;p<3;++p)
    *reinterpret_cast<float4*>(&c2[obase+p*4]) = *reinterpret_cast<float4*>(&acc[p*4]);
}

// merge: h[b,hw,c] = relu(bn2(c2) + bn_sc(res))  (NCHW -> token-major channel-last)
__global__ __launch_bounds__(256) void k_stem_merge(const float* __restrict__ c2,
    const float* __restrict__ res,
    const float* __restrict__ m2,const float* __restrict__ i2,
    const float* __restrict__ g2,const float* __restrict__ b2,
    const float* __restrict__ ms,const float* __restrict__ is,
    const float* __restrict__ gs,const float* __restrict__ bs,
    float* __restrict__ hOut){
  int idx=blockIdx.x*256+threadIdx.x; if(idx>=BSZ*64*9216)return;
  int c=idx&63; int hw=(idx>>6)%9216; int b=idx/(64*9216);
  size_t src=(size_t)(b*64+c)*9216+hw;
  float v=(c2[src]-m2[c])*i2[c]*g2[c]+b2[c];
  float r=(res[src]-ms[c])*is[c]*gs[c]+bs[c];
  hOut[idx]=fmaxf(v+r,0.f);
}

// ---------------- fused LayerNorm + GEMM (N=256, K=64), register-resident W ----
// Thread j=tid owns output column j: W[j][0..63] in 64 VGPRs. LDS = LN'd A tile
// only (broadcast reads, conflict-free). 32 tokens/block, grid 576 (exact).
// FMA loop: 4 rows at a time (acc[4] + <=4 in-flight float4) to keep peak
// pressure ~100 VGPR. No launch_bounds occupancy floor -> compiler won't spill.
template<int OP>
__global__ __launch_bounds__(256) void k_ln_gemm(
    const float* __restrict__ A, const float* __restrict__ lng, const float* __restrict__ lnb,
    const float* __restrict__ W, const float* __restrict__ bias,
    float* __restrict__ out){
  __shared__ __align__(16) float Al[32*64];
  int tid = threadIdx.x;
  int j = tid;
  float wreg[64];
  #pragma unroll
  for(int k4=0;k4<64;k4+=4){
    float4 w4 = *reinterpret_cast<const float4*>(&W[(size_t)j*64+k4]);
    wreg[k4]=w4.x; wreg[k4+1]=w4.y; wreg[k4+2]=w4.z; wreg[k4+3]=w4.w;
  }
  float bv = (OP==1)? bias[j] : 0.f;
  float gg = lng[tid&63], bbv = lnb[tid&63];
  int t0 = blockIdx.x*32;
  // LN: 32 rows, 4 rows per pass (one token per wave), 8 passes
  #pragma unroll
  for(int p=0;p<8;++p){
    int r = p*4 + (tid>>6);
    int c = tid&63;
    float v = A[(size_t)(t0+r)*64+c];
    float s=v, s2=v*v;
    #pragma unroll
    for(int off=32;off>0;off>>=1){ s+=__shfl_xor(s,off); s2+=__shfl_xor(s2,off); }
    float m=s*(1.f/64.f), var=s2*(1.f/64.f)-m*m;
    Al[r*64+c] = (v-m)*rsqrtf(var+1e-5f)*gg + bbv;
  }
  __syncthreads();
  #pragma unroll
  for(int g=0;g<8;++g){            // 8 groups x 4 tokens
    float acc[4];
    #pragma unroll
    for(int r=0;r<4;++r) acc[r]=bv;
    #pragma unroll
    for(int k4=0;k4<64;k4+=4){
      #pragma unroll
      for(int r=0;r<4;++r){
        float4 a = *reinterpret_cast<const float4*>(&Al[(g*4+r)*64 + k4]);
        acc[r] += a.x*wreg[k4] + a.y*wreg[k4+1] + a.z*wreg[k4+2] + a.w*wreg[k4+3];
      }
    }
    #pragma unroll
    for(int r=0;r<4;++r){
      int t = t0 + g*4 + r;
      float v = acc[r];
      if(OP==1) v = 0.5f*v*(1.f+erff(v*0.70710678118f));
      out[(size_t)t*256+j] = v;
    }
  }
}

// ---------------- GEMM N=64 (K=128/256), reg-W k-split + residual (+bias) ----
// Thread (j=tid&63, q=tid>>6) holds W[j][q*KQ..] in regs; A read from global
// with wave-uniform addresses (broadcast). LDS only for the 4-way k reduction.
// Inner FMA in halves of 4 rows to keep peak pressure ~100 VGPR (no spill).
// 48 tokens/block, grid 384 (exact; no duplicate coverage -> res-add safe).
template<int K>
__global__ __launch_bounds__(256) void k_gemm64(
    const float* __restrict__ A, const float* __restrict__ W,
    const float* __restrict__ bias, const float* __restrict__ res,
    float* __restrict__ out){
  constexpr int KQ = K/4;
  __shared__ float Pl[4*8*64];
  int tid = threadIdx.x;
  int j = tid & 63;
  int qu = tid>>6;
  float wreg[KQ];
  const float* wp = W + (size_t)j*K + qu*KQ;
  #pragma unroll
  for(int k4=0;k4<KQ;k4+=4){
    float4 w4 = *reinterpret_cast<const float4*>(wp + k4);
    wreg[k4]=w4.x; wreg[k4+1]=w4.y; wreg[k4+2]=w4.z; wreg[k4+3]=w4.w;
  }
  int t0 = blockIdx.x*48;
  for(int g=0; g<6; ++g){
    int tb = t0 + g*8;
    if(g) __syncthreads();           // prior Pl readers done before overwrite
    #pragma unroll
    for(int h=0;h<2;++h){
      float acc[4];
      #pragma unroll
      for(int r=0;r<4;++r) acc[r]=0.f;
      const float* ap = A + (size_t)(tb+h*4)*K + qu*KQ;
      #pragma unroll
      for(int k4=0;k4<KQ;k4+=4){
        #pragma unroll
        for(int r=0;r<4;++r){
          float4 a = *reinterpret_cast<const float4*>(ap + (size_t)r*K + k4);
          acc[r] += a.x*wreg[k4] + a.y*wreg[k4+1] + a.z*wreg[k4+2] + a.w*wreg[k4+3];
        }
      }
      #pragma unroll
      for(int r=0;r<4;++r) Pl[(qu*8+h*4+r)*64 + j] = acc[r];
    }
    __syncthreads();
    #pragma unroll
    for(int o=0;o<2;++o){
      int idx = o*256 + tid; int r = idx>>6, jj = idx&63; int t = tb + r;
      float v = Pl[r*64+jj] + Pl[512+r*64+jj] + Pl[1024+r*64+jj] + Pl[1536+r*64+jj];
      if(bias) v += bias[jj];
      v += res[(size_t)t*64+jj];
      out[(size_t)t*64+jj] = v;
    }
  }
}

// ---------------- depthwise causal conv (k=4) + silu ----------------
__global__ __launch_bounds__(256) void k_dwconv(const float* __restrict__ xz,
    const float* __restrict__ cw, const float* __restrict__ cb, float* __restrict__ xc){
  int idx=blockIdx.x*256+threadIdx.x; if(idx>=TTOK*128)return;
  int d=idx&127; int t=idx>>7;
  int b=t/LSEQ, l=t%LSEQ;
  float acc=cb[d];
  #pragma unroll
  for(int k=0;k<4;++k){
    int ls=l-3+k;
    if(ls>=0) acc += cw[d*4+k]*xz[(size_t)(b*LSEQ+ls)*256 + d];
  }
  xc[idx]=acc*sigmoidf_(acc);
}

// ---------------- x_proj GEMM (N=36,K=128) + fused delta ----------------
__global__ __launch_bounds__(256,2) void k_xproj_delta(
    const float* __restrict__ A, const float* __restrict__ W,
    const float* __restrict__ dtw, const float* __restrict__ dtb,
    float* __restrict__ dbl, float* __restrict__ delta, int tokensPerBlock){
  __shared__ __align__(16) float lds[37*128 + 56*128 + 56*4 + 512 + 128];
  float* Wl  = lds;               // [128][37] (pad 36->37: conflict-free)
  float* Al  = Wl + 37*128;       // [56][128]
  float* dtv = Al + 56*128;       // [56][4]
  float* dtwl= dtv + 56*4;        // [128][4]
  float* dtbl= dtwl + 512;        // [128]
  int tid=threadIdx.x;
  for(int i=tid;i<36*128;i+=256){int jj=i/128,kk=i%128; Wl[kk*37+jj]=W[i];}
  for(int i=tid;i<512;i+=256) dtwl[i]=dtw[i];
  if(tid<128) dtbl[tid]=dtb[tid];
  int j=tid%36, tg=tid/36;
  bool active = tg<7;
  int tStart=blockIdx.x*tokensPerBlock;
  for(int t0=tStart;t0<tStart+tokensPerBlock;t0+=56){
    __syncthreads();
    for(int i=tid;i<56*128;i+=256){
      int r=i>>7, kk=i&127; int t=t0+r;
      Al[i]=(t<TTOK)?A[(size_t)t*128+kk]:0.f;
    }
    __syncthreads();
    if(active){
      float acc[8];
      #pragma unroll
      for(int i=0;i<8;++i) acc[i]=0.f;
      const float* ar=Al+tg*8*128;
      for(int k=0;k<128;k+=4){
        float w0=Wl[k*37+j],w1=Wl[(k+1)*37+j],w2=Wl[(k+2)*37+j],w3=Wl[(k+3)*37+j];
        #pragma unroll
        for(int i=0;i<8;++i){
          float4 a=*reinterpret_cast<const float4*>(ar+i*128+k);
          acc[i]+=a.x*w0+a.y*w1+a.z*w2+a.w*w3;
        }
      }
      #pragma unroll
      for(int i=0;i<8;++i){
        int t=t0+tg*8+i;
        if(t<TTOK){
          dbl[(size_t)t*36+j]=acc[i];
          if(j<4) dtv[(tg*8+i)*4+j]=acc[i];
        }
      }
    }
    __syncthreads();
    for(int e=tid;e<56*128;e+=256){
      int r=e>>7, d=e&127; int t=t0+r;
      if(t<TTOK){
        float a0=dtv[r*4+0]*dtwl[d*4+0]+dtv[r*4+1]*dtwl[d*4+1]
                +dtv[r*4+2]*dtwl[d*4+2]+dtv[r*4+3]*dtwl[d*4+3]+dtbl[d];
        delta[(size_t)t*128+d]=fmaxf(a0,0.f)+log1pf(expf(-fabsf(a0)));
      }
    }
  }
}

// ---------------- scan phase 1 ----------------
__global__ __launch_bounds__(256) void k_scan1(const float* __restrict__ delta,
    const float* __restrict__ xc, const float* __restrict__ dbl,
    const float* __restrict__ A_log, float* __restrict__ chA, float* __restrict__ chH){
  int idx=blockIdx.x*256+threadIdx.x;
  int n=idx&15; int d=(idx>>4)&127; int chunk=(idx>>11)%NCH; int b=(idx>>11)/NCH;
  float a_const = -expf(A_log[d*16+n]);
  float aprod=1.f, h=0.f;
  int tBase = b*LSEQ + chunk*CS;
  for(int i=0;i<CS;++i){
    int t=tBase+i;
    float dl=delta[(size_t)t*128+d];
    float xv=xc[(size_t)t*128+d];
    float Bv=dbl[(size_t)t*36+4+n];
    float da=expf(dl*a_const);
    h = da*h + dl*xv*Bv;
    aprod *= da;
  }
  chA[idx]=aprod; chH[idx]=h;
}

// ---------------- scan phase 2 ----------------
__global__ __launch_bounds__(256) void k_scan2(const float* __restrict__ chA,
    const float* __restrict__ chH, float* __restrict__ chIn){
  int idx=blockIdx.x*256+threadIdx.x; if(idx>=BSZ*2048) return;
  int b=idx>>11; int dn=idx&2047;
  float H=0.f;
  for(int c=0;c<NCH;++c){
    size_t o=(size_t)(b*NCH+c)*2048+dn;
    chIn[o]=H;
    H = chA[o]*H + chH[o];
  }
}

// ---------------- scan phase 3 + fused gate ----------------
__global__ __launch_bounds__(256) void k_scan3(const float* __restrict__ delta,
    const float* __restrict__ xc, const float* __restrict__ dbl,
    const float* __restrict__ A_log, const float* __restrict__ chIn,
    const float* __restrict__ xz, const float* __restrict__ Dp,
    float* __restrict__ y){
  int tid=threadIdx.x;
  int gid = blockIdx.x*16 + (tid>>4);
  int n = tid&15;
  int d = gid%128; int chunk=(gid/128)%NCH; int b=gid/(128*NCH);
  float a_const = -expf(A_log[d*16+n]);
  float dpv = Dp[d];
  float h = chIn[(size_t)(b*NCH+chunk)*2048 + d*16+n];
  int tBase=b*LSEQ+chunk*CS;
  for(int i=0;i<CS;++i){
    int t=tBase+i;
    float dl=delta[(size_t)t*128+d];
    float xv=xc[(size_t)t*128+d];
    float Bv=dbl[(size_t)t*36+4+n];
    float Cv=dbl[(size_t)t*36+20+n];
    float da=expf(dl*a_const);
    h=da*h+dl*xv*Bv;
    float contrib=h*Cv;
    contrib += __shfl_xor(contrib,1);
    contrib += __shfl_xor(contrib,2);
    contrib += __shfl_xor(contrib,4);
    contrib += __shfl_xor(contrib,8);
    if(n==0){
      float z=xz[(size_t)t*256+128+d];
      y[(size_t)t*128+d]=(contrib + xv*dpv)*(z*sigmoidf_(z));
    }
  }
}

// ---------------- pool stage 1: 256 blocks of partials ----------------
__global__ __launch_bounds__(256) void k_pool1(const float* __restrict__ h,
    float* __restrict__ partial){
  int blk=blockIdx.x;            // b = blk>>7, slice s = blk&127 (72 px each)
  int b=blk>>7, s=blk&127;
  int tid=threadIdx.x; int c=tid&63, sl=tid>>6;
  float sum=0.f;
  int base = s*72;
  for(int p=sl;p<72;p+=4) sum += h[((size_t)b*9216 + base+p)*64 + c];
  __shared__ float ls[256];
  ls[tid]=sum; __syncthreads();
  if(sl==0) partial[(size_t)blk*64+c] = ls[c]+ls[64+c]+ls[128+c]+ls[192+c];
}

// ---------------- pool stage 2 + fc ----------------
__global__ __launch_bounds__(128) void k_pool2(const float* __restrict__ partial,
    const float* __restrict__ fcw, const float* __restrict__ fcb, float* __restrict__ out){
  int tid=threadIdx.x; int b=tid>>6, c=tid&63;
  float s=0.f;
  for(int k=0;k<128;++k) s += partial[(size_t)(b*128+k)*64+c];
  float v=(s/9216.f)*fcw[c];
  #pragma unroll
  for(int off=32;off>0;off>>=1) v+=__shfl_xor(v,off);
  if(c==0) out[b]=v+fcb[0];
}

extern "C" void kernel_launch(void* const* d_in, const int* in_sizes, int n_in,
                              void* d_out, int out_size, void* d_ws, size_t ws_size,
                              hipStream_t stream) {
  const float* x       = (const float*)d_in[0];
  const float* conv1_w = (const float*)d_in[1];
  const float* bn1_g   = (const float*)d_in[2];
  const float* bn1_b   = (const float*)d_in[3];
  const float* conv2_w = (const float*)d_in[4];
  const float* bn2_g   = (const float*)d_in[5];
  const float* bn2_b   = (const float*)d_in[6];
  const float* sc_w    = (const float*)d_in[7];
  const float* sc_g    = (const float*)d_in[8];
  const float* sc_b    = (const float*)d_in[9];
  const float* ln1_g   = (const float*)d_in[10];
  const float* ln1_b   = (const float*)d_in[11];
  const float* in_proj_w = (const float*)d_in[12];
  const float* conv_w  = (const float*)d_in[13];
  const float* conv_b  = (const float*)d_in[14];
  const float* x_proj_w= (const float*)d_in[15];
  const float* dt_w    = (const float*)d_in[16];
  const float* dt_b    = (const float*)d_in[17];
  const float* A_log   = (const float*)d_in[18];
  const float* Dp      = (const float*)d_in[19];
  const float* out_proj_w = (const float*)d_in[20];
  const float* ln2_g   = (const float*)d_in[21];
  const float* ln2_b   = (const float*)d_in[22];
  const float* mlp_w1  = (const float*)d_in[23];
  const float* mlp_b1  = (const float*)d_in[24];
  const float* mlp_w2  = (const float*)d_in[25];
  const float* mlp_b2  = (const float*)d_in[26];
  const float* fc_w    = (const float*)d_in[27];
  const float* fc_b    = (const float*)d_in[28];

  const size_t T = TTOK;
  float* ws    = (float*)d_ws;
  float* bufH  = ws;                  // T*64
  float* bufXZ = bufH  + 64*T;        // T*256 (also stem scratch)
  float* bufXC = bufXZ + 256*T;       // T*128
  float* bufDBL= bufXC + 128*T;       // T*36
  float* bufDLT= bufDBL+ 36*T;        // T*128
  float* bufY  = bufDLT+ 128*T;       // T*128
  float* chA   = bufY  + 128*T;       // B*NCH*2048
  float* chH   = chA   + BSZ*NCH*2048;
  float* chIn  = chH   + BSZ*NCH*2048;
  float* stats = chIn  + BSZ*NCH*2048; // 6*64
  float* partial = stats + 6*64;       // 256*64

  // stem scratch aliases inside bufXZ (each 2*64*9216 = 1179648 floats)
  float* c1   = bufXZ;
  float* c2   = bufXZ + 1179648;
  float* resb = bufXZ + 2*1179648;
  float *m1=stats, *i1=stats+64, *m2=stats+128, *i2=stats+192, *ms=stats+256, *is=stats+320;

  const int NE = BSZ*64*9216;
  const int gE = (NE+255)/256;

  k_stem_conv1<<<gE,256,0,stream>>>(x, conv1_w, sc_w, c1, resb);
  k_bnstats2<<<128,256,0,stream>>>(c1, resb, m1, i1, ms, is);
  k_bnrelu<<<gE,256,0,stream>>>(c1, m1, i1, bn1_g, bn1_b);
  k_stem_conv2<<<BSZ*96*2,256,0,stream>>>(c1, conv2_w, c2);
  k_bnstats<<<64,256,0,stream>>>(c2, m2, i2);
  k_stem_merge<<<gE,256,0,stream>>>(c2, resb, m2, i2, bn2_g, bn2_b, ms, is, sc_g, sc_b, bufH);

  const int gD = (int)((T*128+255)/256);
  for (int i=0;i<6;++i){
    const float* inw  = in_proj_w + (size_t)i*256*64;
    const float* cw   = conv_w    + (size_t)i*128*4;
    const float* cb   = conv_b    + (size_t)i*128;
    const float* xpw  = x_proj_w  + (size_t)i*36*128;
    const float* dtw  = dt_w      + (size_t)i*128*4;
    const float* dtb  = dt_b      + (size_t)i*128;
    const float* alog = A_log     + (size_t)i*128*16;
    const float* dp   = Dp        + (size_t)i*128;
    const float* opw  = out_proj_w+ (size_t)i*64*128;
    const float* w1   = mlp_w1    + (size_t)i*256*64;
    const float* b1   = mlp_b1    + (size_t)i*256;
    const float* w2   = mlp_w2    + (size_t)i*64*256;
    const float* b2   = mlp_b2    + (size_t)i*64;

    k_ln_gemm<0><<<576,256,0,stream>>>(bufH, ln1_g+i*64, ln1_b+i*64, inw, nullptr, bufXZ);
    k_dwconv<<<gD,256,0,stream>>>(bufXZ, cw, cb, bufXC);
    k_xproj_delta<<<330,256,0,stream>>>(bufXC, xpw, dtw, dtb, bufDBL, bufDLT, 56);
    k_scan1<<<BSZ*NCH*2048/256,256,0,stream>>>(bufDLT, bufXC, bufDBL, alog, chA, chH);
    k_scan2<<<(BSZ*2048+255)/256,256,0,stream>>>(chA, chH, chIn);
    k_scan3<<<BSZ*NCH*128/16,256,0,stream>>>(bufDLT, bufXC, bufDBL, alog, chIn, bufXZ, dp, bufY);
    k_gemm64<128><<<384,256,0,stream>>>(bufY, opw, nullptr, bufH, bufH);
    k_ln_gemm<1><<<576,256,0,stream>>>(bufH, ln2_g+i*64, ln2_b+i*64, w1, b1, bufXZ);
    k_gemm64<256><<<384,256,0,stream>>>(bufXZ, w2, b2, bufH, bufH);
  }

  k_pool1<<<256,256,0,stream>>>(bufH, partial);
  k_pool2<<<1,128,0,stream>>>(partial, fc_w, fc_b, (float*)d_out);
}

// Round 7
// 2384.475 us; speedup vs baseline: 1.5647x; 1.0200x over previous
//
#include <hip/hip_runtime.h>
#include <math.h>

// MambaNet forward: stem (conv/BN/relu) -> 6x [LN -> Mamba -> LN -> MLP] -> pool -> fc
// All f32. T = 18432 tokens (B=2, L=9216), d_model=64, d_inner=128, N_state=16.

#define TTOK 18432
#define LSEQ 9216
#define BSZ 2
#define CS 96     // scan chunk size
#define NCH 96    // number of chunks (CS*NCH == LSEQ)

__device__ __forceinline__ float sigmoidf_(float x){ return 1.f/(1.f+expf(-x)); }

// ---------------- Stem ----------------
__global__ __launch_bounds__(256) void k_stem_conv1(const float* __restrict__ x,
    const float* __restrict__ w1, const float* __restrict__ scw,
    float* __restrict__ c1, float* __restrict__ res){
  int idx = blockIdx.x*256 + threadIdx.x;
  if (idx >= BSZ*64*9216) return;
  int hw = idx % 9216; int c = (idx/9216) & 63; int b = idx/(9216*64);
  int h = hw/96, w = hw%96;
  const float* xb = x + b*9216;
  float acc = 0.f;
  for (int dh=-1; dh<=1; ++dh){
    int hh=h+dh; if(hh<0||hh>=96) continue;
    for (int dw=-1; dw<=1; ++dw){
      int ww=w+dw; if(ww<0||ww>=96) continue;
      acc += xb[hh*96+ww]*w1[c*9+(dh+1)*3+(dw+1)];
    }
  }
  c1[idx]=acc;
  res[idx]=xb[hw]*scw[c];
}

// per-channel batch stats for TWO tensors in one launch (128 blocks)
__global__ __launch_bounds__(256) void k_bnstats2(const float* __restrict__ srcA,
    const float* __restrict__ srcB,
    float* __restrict__ meanA, float* __restrict__ istdA,
    float* __restrict__ meanB, float* __restrict__ istdB){
  int c = blockIdx.x & 63; int tid = threadIdx.x;
  const float* src = (blockIdx.x < 64)? srcA : srcB;
  float* mean = (blockIdx.x < 64)? meanA : meanB;
  float* istd = (blockIdx.x < 64)? istdA : istdB;
  float s=0.f, s2=0.f;
  for (int b=0;b<BSZ;++b){
    const float* p = src + (size_t)(b*64+c)*9216;
    for (int i=tid;i<9216;i+=256){ float v=p[i]; s+=v; s2+=v*v; }
  }
  __shared__ float ls[256], ls2[256];
  ls[tid]=s; ls2[tid]=s2; __syncthreads();
  for(int off=128;off>0;off>>=1){
    if(tid<off){ ls[tid]+=ls[tid+off]; ls2[tid]+=ls2[tid+off]; }
    __syncthreads();
  }
  if(tid==0){
    float m=ls[0]/18432.f; float v=ls2[0]/18432.f - m*m;
    mean[c]=m; istd[c]=rsqrtf(v+1e-5f);
  }
}

__global__ __launch_bounds__(256) void k_bnstats(const float* __restrict__ src,
    float* __restrict__ mean, float* __restrict__ istd){
  int c = blockIdx.x; int tid = threadIdx.x;
  float s=0.f, s2=0.f;
  for (int b=0;b<BSZ;++b){
    const float* p = src + (size_t)(b*64+c)*9216;
    for (int i=tid;i<9216;i+=256){ float v=p[i]; s+=v; s2+=v*v; }
  }
  __shared__ float ls[256], ls2[256];
  ls[tid]=s; ls2[tid]=s2; __syncthreads();
  for(int off=128;off>0;off>>=1){
    if(tid<off){ ls[tid]+=ls[tid+off]; ls2[tid]+=ls2[tid+off]; }
    __syncthreads();
  }
  if(tid==0){
    float m=ls[0]/18432.f; float v=ls2[0]/18432.f - m*m;
    mean[c]=m; istd[c]=rsqrtf(v+1e-5f);
  }
}

__global__ __launch_bounds__(256) void k_bnrelu(float* __restrict__ t,
    const float* __restrict__ mean, const float* __restrict__ istd,
    const float* __restrict__ g, const float* __restrict__ bb){
  int idx = blockIdx.x*256+threadIdx.x; if(idx>=BSZ*64*9216) return;
  int c=(idx/9216)&63;
  float v=(t[idx]-mean[c])*istd[c]*g[c]+bb[c];
  t[idx]=fmaxf(v,0.f);
}

// Tiled direct conv 64->64, 3x3. Block = (b, out-row h, half-row wh).
__global__ __launch_bounds__(256) void k_stem_conv2(const float* __restrict__ h1,
    const float* __restrict__ w2, float* __restrict__ c2){
  __shared__ __align__(16) float in_lds[16*156];   // [ci][3][52]
  __shared__ float w_lds[64*145];                  // [co][16*9 (+1 pad)]
  int blk=blockIdx.x;
  int wh=blk&1, h=(blk>>1)%96, b=blk/(2*96);
  int tid=threadIdx.x;
  int co=tid&63, pg=tid>>6;
  float acc[12];
  #pragma unroll
  for(int i=0;i<12;++i) acc[i]=0.f;
  int wbase = wh*48;
  const float* hb = h1 + (size_t)b*64*9216;
  for(int cc=0;cc<4;++cc){
    __syncthreads();
    for(int e=tid;e<16*3*50;e+=256){
      int ci=e/150, rr=e%150; int tr=rr/50, wl=rr%50;
      int hh=h+tr-1, ww=wbase+wl-1;
      float v=0.f;
      if(hh>=0&&hh<96&&ww>=0&&ww<96) v=hb[(size_t)(cc*16+ci)*9216 + hh*96+ww];
      in_lds[ci*156 + tr*52 + wl]=v;
    }
    for(int e=tid;e<64*144;e+=256){
      int c_=e/144, r=e%144;
      w_lds[c_*145+r]=w2[(size_t)c_*576 + cc*144 + r];
    }
    __syncthreads();
    for(int ci=0;ci<16;++ci){
      float wr[9];
      #pragma unroll
      for(int t=0;t<9;++t) wr[t]=w_lds[co*145+ci*9+t];
      const float* ibase = in_lds + ci*156;
      #pragma unroll
      for(int tr=0;tr<3;++tr){
        const float* row = ibase + tr*52 + pg*12;
        float win[14];
        #pragma unroll
        for(int q=0;q<14;++q) win[q]=row[q];
        #pragma unroll
        for(int p=0;p<12;++p)
          acc[p] += win[p]*wr[tr*3+0] + win[p+1]*wr[tr*3+1] + win[p+2]*wr[tr*3+2];
      }
    }
  }
  size_t obase=(size_t)(b*64+co)*9216 + h*96 + wbase + pg*12;
  #pragma unroll
  for(int p=0;p<3;++p)
    *reinterpret_cast<float4*>(&c2[obase+p*4]) = *reinterpret_cast<float4*>(&acc[p*4]);
}

// merge: h[b,hw,c] = relu(bn2(c2) + bn_sc(res))  (NCHW -> token-major channel-last)
__global__ __launch_bounds__(256) void k_stem_merge(const float* __restrict__ c2,
    const float* __restrict__ res,
    const float* __restrict__ m2,const float* __restrict__ i2,
    const float* __restrict__ g2,const float* __restrict__ b2,
    const float* __restrict__ ms,const float* __restrict__ is,
    const float* __restrict__ gs,const float* __restrict__ bs,
    float* __restrict__ hOut){
  int idx=blockIdx.x*256+threadIdx.x; if(idx>=BSZ*64*9216)return;
  int c=idx&63; int hw=(idx>>6)%9216; int b=idx/(64*9216);
  size_t src=(size_t)(b*64+c)*9216+hw;
  float v=(c2[src]-m2[c])*i2[c]*g2[c]+b2[c];
  float r=(res[src]-ms[c])*is[c]*gs[c]+bs[c];
  hOut[idx]=fmaxf(v+r,0.f);
}

// ---------------- fused LayerNorm + GEMM (N=256, K=64) v2 ------------------
// Transposed LN tile Al[c][r] (pad 36): main-loop reads are float4 over 4 rows
// at wave-uniform addresses (broadcast, conflict-free). Thread = 2 output
// cols (c0=2*(tid&127)) x k-half (q=tid>>7): wreg 2x32 = 64 VGPR, 8 FMA per
// ds_read_b128. g-loop rolled (I-cache fit); inner unroll 4 caps in-flight
// reads so peak pressure < 128 VGPR (4 waves/SIMD). Cross-half reduce via
// double-buffered Pl, one barrier per group. 32 tokens/block, grid 576.
template<int OP>
__global__ __launch_bounds__(256) void k_ln_gemm(
    const float* __restrict__ A, const float* __restrict__ lng, const float* __restrict__ lnb,
    const float* __restrict__ W, const float* __restrict__ bias,
    float* __restrict__ out){
  __shared__ __align__(16) float Al[64*36];
  __shared__ __align__(16) float Pl[2][4*256];
  int tid = threadIdx.x;
  int j2 = tid & 127;
  int q  = tid >> 7;             // wave-uniform (waves 0,1 -> q=0; 2,3 -> q=1)
  int c0 = j2*2;
  float w0r[32], w1r[32];
  {
    const float* wp0 = W + (size_t)c0*64 + q*32;
    const float* wp1 = wp0 + 64;
    #pragma unroll
    for(int k4=0;k4<32;k4+=4){
      float4 a = *reinterpret_cast<const float4*>(wp0+k4);
      w0r[k4]=a.x; w0r[k4+1]=a.y; w0r[k4+2]=a.z; w0r[k4+3]=a.w;
      float4 b = *reinterpret_cast<const float4*>(wp1+k4);
      w1r[k4]=b.x; w1r[k4+1]=b.y; w1r[k4+2]=b.z; w1r[k4+3]=b.w;
    }
  }
  float bv0=0.f, bv1=0.f;
  if(OP==1){ bv0=bias[c0]; bv1=bias[c0+1]; }
  float gg = lng[tid&63], bbv = lnb[tid&63];
  int t0 = blockIdx.x*32;
  // LN: 32 rows, 4 per pass (token per wave), write transposed Al[c][r]
  #pragma unroll
  for(int p=0;p<8;++p){
    int r = p*4 + (tid>>6);
    int c = tid&63;
    float v = A[(size_t)(t0+r)*64+c];
    float s=v, s2=v*v;
    #pragma unroll
    for(int off=32;off>0;off>>=1){ s+=__shfl_xor(s,off); s2+=__shfl_xor(s2,off); }
    float m=s*(1.f/64.f), var=s2*(1.f/64.f)-m*m;
    Al[c*36+r] = (v-m)*rsqrtf(var+1e-5f)*gg + bbv;
  }
  __syncthreads();
  const float* alk = Al + q*32*36;
  #pragma unroll 1
  for(int g=0;g<8;++g){
    float acc0[4], acc1[4];
    #pragma unroll
    for(int r=0;r<4;++r){ acc0[r]=0.f; acc1[r]=0.f; }
    const float* ap = alk + g*4;
    #pragma unroll 4
    for(int kk=0;kk<32;++kk){
      float4 a = *reinterpret_cast<const float4*>(ap + kk*36);
      float w0=w0r[kk], w1=w1r[kk];
      acc0[0]+=a.x*w0; acc0[1]+=a.y*w0; acc0[2]+=a.z*w0; acc0[3]+=a.w*w0;
      acc1[0]+=a.x*w1; acc1[1]+=a.y*w1; acc1[2]+=a.z*w1; acc1[3]+=a.w*w1;
    }
    float* pb = Pl[g&1];
    if(q==1){
      #pragma unroll
      for(int r=0;r<4;++r){
        float2 v2; v2.x=acc0[r]; v2.y=acc1[r];
        *reinterpret_cast<float2*>(&pb[r*256 + c0]) = v2;
      }
    }
    __syncthreads();
    if(q==0){
      #pragma unroll
      for(int r=0;r<4;++r){
        float2 pv = *reinterpret_cast<const float2*>(&pb[r*256 + c0]);
        float v0 = acc0[r] + pv.x + bv0;
        float v1 = acc1[r] + pv.y + bv1;
        if(OP==1){
          v0 = 0.5f*v0*(1.f+erff(v0*0.70710678118f));
          v1 = 0.5f*v1*(1.f+erff(v1*0.70710678118f));
        }
        int t = t0 + g*4 + r;
        float2 o; o.x=v0; o.y=v1;
        *reinterpret_cast<float2*>(&out[(size_t)t*256 + c0]) = o;
      }
    }
  }
}

// ---------------- GEMM N=64 (K=128/256), reg-W k-split + residual (+bias) ----
// g-loop rolled (#pragma unroll 1): round-6 full unroll was ~38KB of code ->
// I-cache thrash. Body now ~police 5KB.
template<int K>
__global__ __launch_bounds__(256) void k_gemm64(
    const float* __restrict__ A, const float* __restrict__ W,
    const float* __restrict__ bias, const float* __restrict__ res,
    float* __restrict__ out){
  constexpr int KQ = K/4;
  __shared__ float Pl[4*8*64];
  int tid = threadIdx.x;
  int j = tid & 63;
  int qu = tid>>6;
  float wreg[KQ];
  const float* wp = W + (size_t)j*K + qu*KQ;
  #pragma unroll
  for(int k4=0;k4<KQ;k4+=4){
    float4 w4 = *reinterpret_cast<const float4*>(wp + k4);
    wreg[k4]=w4.x; wreg[k4+1]=w4.y; wreg[k4+2]=w4.z; wreg[k4+3]=w4.w;
  }
  int t0 = blockIdx.x*48;
  #pragma unroll 1
  for(int g=0; g<6; ++g){
    int tb = t0 + g*8;
    if(g) __syncthreads();           // prior Pl readers done before overwrite
    #pragma unroll
    for(int h=0;h<2;++h){
      float acc[4];
      #pragma unroll
      for(int r=0;r<4;++r) acc[r]=0.f;
      const float* ap = A + (size_t)(tb+h*4)*K + qu*KQ;
      #pragma unroll 4
      for(int k4=0;k4<KQ;k4+=4){
        #pragma unroll
        for(int r=0;r<4;++r){
          float4 a = *reinterpret_cast<const float4*>(ap + (size_t)r*K + k4);
          acc[r] += a.x*wreg[k4] + a.y*wreg[k4+1] + a.z*wreg[k4+2] + a.w*wreg[k4+3];
        }
      }
      #pragma unroll
      for(int r=0;r<4;++r) Pl[(qu*8+h*4+r)*64 + j] = acc[r];
    }
    __syncthreads();
    #pragma unroll
    for(int o=0;o<2;++o){
      int idx = o*256 + tid; int r = idx>>6, jj = idx&63; int t = tb + r;
      float v = Pl[r*64+jj] + Pl[512+r*64+jj] + Pl[1024+r*64+jj] + Pl[1536+r*64+jj];
      if(bias) v += bias[jj];
      v += res[(size_t)t*64+jj];
      out[(size_t)t*64+jj] = v;
    }
  }
}

// ---------------- depthwise causal conv (k=4) + silu ----------------
__global__ __launch_bounds__(256) void k_dwconv(const float* __restrict__ xz,
    const float* __restrict__ cw, const float* __restrict__ cb, float* __restrict__ xc){
  int idx=blockIdx.x*256+threadIdx.x; if(idx>=TTOK*128)return;
  int d=idx&127; int t=idx>>7;
  int b=t/LSEQ, l=t%LSEQ;
  float acc=cb[d];
  #pragma unroll
  for(int k=0;k<4;++k){
    int ls=l-3+k;
    if(ls>=0) acc += cw[d*4+k]*xz[(size_t)(b*LSEQ+ls)*256 + d];
  }
  xc[idx]=acc*sigmoidf_(acc);
}

// ---------------- x_proj GEMM (N=36,K=128) + fused delta ----------------
__global__ __launch_bounds__(256,2) void k_xproj_delta(
    const float* __restrict__ A, const float* __restrict__ W,
    const float* __restrict__ dtw, const float* __restrict__ dtb,
    float* __restrict__ dbl, float* __restrict__ delta, int tokensPerBlock){
  __shared__ __align__(16) float lds[37*128 + 56*128 + 56*4 + 512 + 128];
  float* Wl  = lds;               // [128][37] (pad 36->37: conflict-free)
  float* Al  = Wl + 37*128;       // [56][128]
  float* dtv = Al + 56*128;       // [56][4]
  float* dtwl= dtv + 56*4;        // [128][4]
  float* dtbl= dtwl + 512;        // [128]
  int tid=threadIdx.x;
  for(int i=tid;i<36*128;i+=256){int jj=i/128,kk=i%128; Wl[kk*37+jj]=W[i];}
  for(int i=tid;i<512;i+=256) dtwl[i]=dtw[i];
  if(tid<128) dtbl[tid]=dtb[tid];
  int j=tid%36, tg=tid/36;
  bool active = tg<7;
  int tStart=blockIdx.x*tokensPerBlock;
  for(int t0=tStart;t0<tStart+tokensPerBlock;t0+=56){
    __syncthreads();
    for(int i=tid;i<56*128;i+=256){
      int r=i>>7, kk=i&127; int t=t0+r;
      Al[i]=(t<TTOK)?A[(size_t)t*128+kk]:0.f;
    }
    __syncthreads();
    if(active){
      float acc[8];
      #pragma unroll
      for(int i=0;i<8;++i) acc[i]=0.f;
      const float* ar=Al+tg*8*128;
      for(int k=0;k<128;k+=4){
        float w0=Wl[k*37+j],w1=Wl[(k+1)*37+j],w2=Wl[(k+2)*37+j],w3=Wl[(k+3)*37+j];
        #pragma unroll
        for(int i=0;i<8;++i){
          float4 a=*reinterpret_cast<const float4*>(ar+i*128+k);
          acc[i]+=a.x*w0+a.y*w1+a.z*w2+a.w*w3;
        }
      }
      #pragma unroll
      for(int i=0;i<8;++i){
        int t=t0+tg*8+i;
        if(t<TTOK){
          dbl[(size_t)t*36+j]=acc[i];
          if(j<4) dtv[(tg*8+i)*4+j]=acc[i];
        }
      }
    }
    __syncthreads();
    for(int e=tid;e<56*128;e+=256){
      int r=e>>7, d=e&127; int t=t0+r;
      if(t<TTOK){
        float a0=dtv[r*4+0]*dtwl[d*4+0]+dtv[r*4+1]*dtwl[d*4+1]
                +dtv[r*4+2]*dtwl[d*4+2]+dtv[r*4+3]*dtwl[d*4+3]+dtbl[d];
        delta[(size_t)t*128+d]=fmaxf(a0,0.f)+log1pf(expf(-fabsf(a0)));
      }
    }
  }
}

// ---------------- scan phase 1 ----------------
__global__ __launch_bounds__(256) void k_scan1(const float* __restrict__ delta,
    const float* __restrict__ xc, const float* __restrict__ dbl,
    const float* __restrict__ A_log, float* __restrict__ chA, float* __restrict__ chH){
  int idx=blockIdx.x*256+threadIdx.x;
  int n=idx&15; int d=(idx>>4)&127; int chunk=(idx>>11)%NCH; int b=(idx>>11)/NCH;
  float a_const = -expf(A_log[d*16+n]);
  float aprod=1.f, h=0.f;
  int tBase = b*LSEQ + chunk*CS;
  for(int i=0;i<CS;++i){
    int t=tBase+i;
    float dl=delta[(size_t)t*128+d];
    float xv=xc[(size_t)t*128+d];
    float Bv=dbl[(size_t)t*36+4+n];
    float da=expf(dl*a_const);
    h = da*h + dl*xv*Bv;
    aprod *= da;
  }
  chA[idx]=aprod; chH[idx]=h;
}

// ---------------- scan phase 2 ----------------
__global__ __launch_bounds__(256) void k_scan2(const float* __restrict__ chA,
    const float* __restrict__ chH, float* __restrict__ chIn){
  int idx=blockIdx.x*256+threadIdx.x; if(idx>=BSZ*2048) return;
  int b=idx>>11; int dn=idx&2047;
  float H=0.f;
  for(int c=0;c<NCH;++c){
    size_t o=(size_t)(b*NCH+c)*2048+dn;
    chIn[o]=H;
    H = chA[o]*H + chH[o];
  }
}

// ---------------- scan phase 3 + fused gate ----------------
__global__ __launch_bounds__(256) void k_scan3(const float* __restrict__ delta,
    const float* __restrict__ xc, const float* __restrict__ dbl,
    const float* __restrict__ A_log, const float* __restrict__ chIn,
    const float* __restrict__ xz, const float* __restrict__ Dp,
    float* __restrict__ y){
  int tid=threadIdx.x;
  int gid = blockIdx.x*16 + (tid>>4);
  int n = tid&15;
  int d = gid%128; int chunk=(gid/128)%NCH; int b=gid/(128*NCH);
  float a_const = -expf(A_log[d*16+n]);
  float dpv = Dp[d];
  float h = chIn[(size_t)(b*NCH+chunk)*2048 + d*16+n];
  int tBase=b*LSEQ+chunk*CS;
  for(int i=0;i<CS;++i){
    int t=tBase+i;
    float dl=delta[(size_t)t*128+d];
    float xv=xc[(size_t)t*128+d];
    float Bv=dbl[(size_t)t*36+4+n];
    float Cv=dbl[(size_t)t*36+20+n];
    float da=expf(dl*a_const);
    h=da*h+dl*xv*Bv;
    float contrib=h*Cv;
    contrib += __shfl_xor(contrib,1);
    contrib += __shfl_xor(contrib,2);
    contrib += __shfl_xor(contrib,4);
    contrib += __shfl_xor(contrib,8);
    if(n==0){
      float z=xz[(size_t)t*256+128+d];
      y[(size_t)t*128+d]=(contrib + xv*dpv)*(z*sigmoidf_(z));
    }
  }
}

// ---------------- pool stage 1: 256 blocks of partials ----------------
__global__ __launch_bounds__(256) void k_pool1(const float* __restrict__ h,
    float* __restrict__ partial){
  int blk=blockIdx.x;            // b = blk>>7, slice s = blk&127 (72 px each)
  int b=blk>>7, s=blk&127;
  int tid=threadIdx.x; int c=tid&63, sl=tid>>6;
  float sum=0.f;
  int base = s*72;
  for(int p=sl;p<72;p+=4) sum += h[((size_t)b*9216 + base+p)*64 + c];
  __shared__ float ls[256];
  ls[tid]=sum; __syncthreads();
  if(sl==0) partial[(size_t)blk*64+c] = ls[c]+ls[64+c]+ls[128+c]+ls[192+c];
}

// ---------------- pool stage 2 + fc ----------------
__global__ __launch_bounds__(128) void k_pool2(const float* __restrict__ partial,
    const float* __restrict__ fcw, const float* __restrict__ fcb, float* __restrict__ out){
  int tid=threadIdx.x; int b=tid>>6, c=tid&63;
  float s=0.f;
  for(int k=0;k<128;++k) s += partial[(size_t)(b*128+k)*64+c];
  float v=(s/9216.f)*fcw[c];
  #pragma unroll
  for(int off=32;off>0;off>>=1) v+=__shfl_xor(v,off);
  if(c==0) out[b]=v+fcb[0];
}

extern "C" void kernel_launch(void* const* d_in, const int* in_sizes, int n_in,
                              void* d_out, int out_size, void* d_ws, size_t ws_size,
                              hipStream_t stream) {
  const float* x       = (const float*)d_in[0];
  const float* conv1_w = (const float*)d_in[1];
  const float* bn1_g   = (const float*)d_in[2];
  const float* bn1_b   = (const float*)d_in[3];
  const float* conv2_w = (const float*)d_in[4];
  const float* bn2_g   = (const float*)d_in[5];
  const float* bn2_b   = (const float*)d_in[6];
  const float* sc_w    = (const float*)d_in[7];
  const float* sc_g    = (const float*)d_in[8];
  const float* sc_b    = (const float*)d_in[9];
  const float* ln1_g   = (const float*)d_in[10];
  const float* ln1_b   = (const float*)d_in[11];
  const float* in_proj_w = (const float*)d_in[12];
  const float* conv_w  = (const float*)d_in[13];
  const float* conv_b  = (const float*)d_in[14];
  const float* x_proj_w= (const float*)d_in[15];
  const float* dt_w    = (const float*)d_in[16];
  const float* dt_b    = (const float*)d_in[17];
  const float* A_log   = (const float*)d_in[18];
  const float* Dp      = (const float*)d_in[19];
  const float* out_proj_w = (const float*)d_in[20];
  const float* ln2_g   = (const float*)d_in[21];
  const float* ln2_b   = (const float*)d_in[22];
  const float* mlp_w1  = (const float*)d_in[23];
  const float* mlp_b1  = (const float*)d_in[24];
  const float* mlp_w2  = (const float*)d_in[25];
  const float* mlp_b2  = (const float*)d_in[26];
  const float* fc_w    = (const float*)d_in[27];
  const float* fc_b    = (const float*)d_in[28];

  const size_t T = TTOK;
  float* ws    = (float*)d_ws;
  float* bufH  = ws;                  // T*64
  float* bufXZ = bufH  + 64*T;        // T*256 (also stem scratch)
  float* bufXC = bufXZ + 256*T;       // T*128
  float* bufDBL= bufXC + 128*T;       // T*36
  float* bufDLT= bufDBL+ 36*T;        // T*128
  float* bufY  = bufDLT+ 128*T;       // T*128
  float* chA   = bufY  + 128*T;       // B*NCH*2048
  float* chH   = chA   + BSZ*NCH*2048;
  float* chIn  = chH   + BSZ*NCH*2048;
  float* stats = chIn  + BSZ*NCH*2048; // 6*64
  float* partial = stats + 6*64;       // 256*64

  // stem scratch aliases inside bufXZ (each 2*64*9216 = 1179648 floats)
  float* c1   = bufXZ;
  float* c2   = bufXZ + 1179648;
  float* resb = bufXZ + 2*1179648;
  float *m1=stats, *i1=stats+64, *m2=stats+128, *i2=stats+192, *ms=stats+256, *is=stats+320;

  const int NE = BSZ*64*9216;
  const int gE = (NE+255)/256;

  k_stem_conv1<<<gE,256,0,stream>>>(x, conv1_w, sc_w, c1, resb);
  k_bnstats2<<<128,256,0,stream>>>(c1, resb, m1, i1, ms, is);
  k_bnrelu<<<gE,256,0,stream>>>(c1, m1, i1, bn1_g, bn1_b);
  k_stem_conv2<<<BSZ*96*2,256,0,stream>>>(c1, conv2_w, c2);
  k_bnstats<<<64,256,0,stream>>>(c2, m2, i2);
  k_stem_merge<<<gE,256,0,stream>>>(c2, resb, m2, i2, bn2_g, bn2_b, ms, is, sc_g, sc_b, bufH);

  const int gD = (int)((T*128+255)/256);
  for (int i=0;i<6;++i){
    const float* inw  = in_proj_w + (size_t)i*256*64;
    const float* cw   = conv_w    + (size_t)i*128*4;
    const float* cb   = conv_b    + (size_t)i*128;
    const float* xpw  = x_proj_w  + (size_t)i*36*128;
    const float* dtw  = dt_w      + (size_t)i*128*4;
    const float* dtb  = dt_b      + (size_t)i*128;
    const float* alog = A_log     + (size_t)i*128*16;
    const float* dp   = Dp        + (size_t)i*128;
    const float* opw  = out_proj_w+ (size_t)i*64*128;
    const float* w1   = mlp_w1    + (size_t)i*256*64;
    const float* b1   = mlp_b1    + (size_t)i*256;
    const float* w2   = mlp_w2    + (size_t)i*64*256;
    const float* b2   = mlp_b2    + (size_t)i*64;

    k_ln_gemm<0><<<576,256,0,stream>>>(bufH, ln1_g+i*64, ln1_b+i*64, inw, nullptr, bufXZ);
    k_dwconv<<<gD,256,0,stream>>>(bufXZ, cw, cb, bufXC);
    k_xproj_delta<<<330,256,0,stream>>>(bufXC, xpw, dtw, dtb, bufDBL, bufDLT, 56);
    k_scan1<<<BSZ*NCH*2048/256,256,0,stream>>>(bufDLT, bufXC, bufDBL, alog, chA, chH);
    k_scan2<<<(BSZ*2048+255)/256,256,0,stream>>>(chA, chH, chIn);
    k_scan3<<<BSZ*NCH*128/16,256,0,stream>>>(bufDLT, bufXC, bufDBL, alog, chIn, bufXZ, dp, bufY);
    k_gemm64<128><<<384,256,0,stream>>>(bufY, opw, nullptr, bufH, bufH);
    k_ln_gemm<1><<<576,256,0,stream>>>(bufH, ln2_g+i*64, ln2_b+i*64, w1, b1, bufXZ);
    k_gemm64<256><<<384,256,0,stream>>>(bufXZ, w2, b2, bufH, bufH);
  }

  k_pool1<<<256,256,0,stream>>>(bufH, partial);
  k_pool2<<<1,128,0,stream>>>(partial, fc_w, fc_b, (float*)d_out);
}

// Round 8
// 1819.931 us; speedup vs baseline: 2.0501x; 1.3102x over previous
//
#include <hip/hip_runtime.h>
#include <math.h>

// MambaNet forward: stem (conv/BN/relu) -> 6x [LN -> Mamba -> LN -> MLP] -> pool -> fc
// All f32. T = 18432 tokens (B=2, L=9216), d_model=64, d_inner=128, N_state=16.

#define TTOK 18432
#define LSEQ 9216
#define BSZ 2
#define CS 96     // scan chunk size
#define NCH 96    // number of chunks (CS*NCH == LSEQ)

__device__ __forceinline__ float sigmoidf_(float x){ return 1.f/(1.f+expf(-x)); }

// ---------------- Stem ----------------
__global__ __launch_bounds__(256) void k_stem_conv1(const float* __restrict__ x,
    const float* __restrict__ w1, const float* __restrict__ scw,
    float* __restrict__ c1, float* __restrict__ res){
  int idx = blockIdx.x*256 + threadIdx.x;
  if (idx >= BSZ*64*9216) return;
  int hw = idx % 9216; int c = (idx/9216) & 63; int b = idx/(9216*64);
  int h = hw/96, w = hw%96;
  const float* xb = x + b*9216;
  float acc = 0.f;
  for (int dh=-1; dh<=1; ++dh){
    int hh=h+dh; if(hh<0||hh>=96) continue;
    for (int dw=-1; dw<=1; ++dw){
      int ww=w+dw; if(ww<0||ww>=96) continue;
      acc += xb[hh*96+ww]*w1[c*9+(dh+1)*3+(dw+1)];
    }
  }
  c1[idx]=acc;
  res[idx]=xb[hw]*scw[c];
}

// per-channel batch stats for TWO tensors in one launch (128 blocks)
__global__ __launch_bounds__(256) void k_bnstats2(const float* __restrict__ srcA,
    const float* __restrict__ srcB,
    float* __restrict__ meanA, float* __restrict__ istdA,
    float* __restrict__ meanB, float* __restrict__ istdB){
  int c = blockIdx.x & 63; int tid = threadIdx.x;
  const float* src = (blockIdx.x < 64)? srcA : srcB;
  float* mean = (blockIdx.x < 64)? meanA : meanB;
  float* istd = (blockIdx.x < 64)? istdA : istdB;
  float s=0.f, s2=0.f;
  for (int b=0;b<BSZ;++b){
    const float* p = src + (size_t)(b*64+c)*9216;
    for (int i=tid;i<9216;i+=256){ float v=p[i]; s+=v; s2+=v*v; }
  }
  __shared__ float ls[256], ls2[256];
  ls[tid]=s; ls2[tid]=s2; __syncthreads();
  for(int off=128;off>0;off>>=1){
    if(tid<off){ ls[tid]+=ls[tid+off]; ls2[tid]+=ls2[tid+off]; }
    __syncthreads();
  }
  if(tid==0){
    float m=ls[0]/18432.f; float v=ls2[0]/18432.f - m*m;
    mean[c]=m; istd[c]=rsqrtf(v+1e-5f);
  }
}

__global__ __launch_bounds__(256) void k_bnstats(const float* __restrict__ src,
    float* __restrict__ mean, float* __restrict__ istd){
  int c = blockIdx.x; int tid = threadIdx.x;
  float s=0.f, s2=0.f;
  for (int b=0;b<BSZ;++b){
    const float* p = src + (size_t)(b*64+c)*9216;
    for (int i=tid;i<9216;i+=256){ float v=p[i]; s+=v; s2+=v*v; }
  }
  __shared__ float ls[256], ls2[256];
  ls[tid]=s; ls2[tid]=s2; __syncthreads();
  for(int off=128;off>0;off>>=1){
    if(tid<off){ ls[tid]+=ls[tid+off]; ls2[tid]+=ls2[tid+off]; }
    __syncthreads();
  }
  if(tid==0){
    float m=ls[0]/18432.f; float v=ls2[0]/18432.f - m*m;
    mean[c]=m; istd[c]=rsqrtf(v+1e-5f);
  }
}

__global__ __launch_bounds__(256) void k_bnrelu(float* __restrict__ t,
    const float* __restrict__ mean, const float* __restrict__ istd,
    const float* __restrict__ g, const float* __restrict__ bb){
  int idx = blockIdx.x*256+threadIdx.x; if(idx>=BSZ*64*9216) return;
  int c=(idx/9216)&63;
  float v=(t[idx]-mean[c])*istd[c]*g[c]+bb[c];
  t[idx]=fmaxf(v,0.f);
}

// Tiled direct conv 64->64, 3x3. Block = (b, out-row h, half-row wh).
__global__ __launch_bounds__(256) void k_stem_conv2(const float* __restrict__ h1,
    const float* __restrict__ w2, float* __restrict__ c2){
  __shared__ __align__(16) float in_lds[16*156];   // [ci][3][52]
  __shared__ float w_lds[64*145];                  // [co][16*9 (+1 pad)]
  int blk=blockIdx.x;
  int wh=blk&1, h=(blk>>1)%96, b=blk/(2*96);
  int tid=threadIdx.x;
  int co=tid&63, pg=tid>>6;
  float acc[12];
  #pragma unroll
  for(int i=0;i<12;++i) acc[i]=0.f;
  int wbase = wh*48;
  const float* hb = h1 + (size_t)b*64*9216;
  for(int cc=0;cc<4;++cc){
    __syncthreads();
    for(int e=tid;e<16*3*50;e+=256){
      int ci=e/150, rr=e%150; int tr=rr/50, wl=rr%50;
      int hh=h+tr-1, ww=wbase+wl-1;
      float v=0.f;
      if(hh>=0&&hh<96&&ww>=0&&ww<96) v=hb[(size_t)(cc*16+ci)*9216 + hh*96+ww];
      in_lds[ci*156 + tr*52 + wl]=v;
    }
    for(int e=tid;e<64*144;e+=256){
      int c_=e/144, r=e%144;
      w_lds[c_*145+r]=w2[(size_t)c_*576 + cc*144 + r];
    }
    __syncthreads();
    for(int ci=0;ci<16;++ci){
      float wr[9];
      #pragma unroll
      for(int t=0;t<9;++t) wr[t]=w_lds[co*145+ci*9+t];
      const float* ibase = in_lds + ci*156;
      #pragma unroll
      for(int tr=0;tr<3;++tr){
        const float* row = ibase + tr*52 + pg*12;
        float win[14];
        #pragma unroll
        for(int q=0;q<14;++q) win[q]=row[q];
        #pragma unroll
        for(int p=0;p<12;++p)
          acc[p] += win[p]*wr[tr*3+0] + win[p+1]*wr[tr*3+1] + win[p+2]*wr[tr*3+2];
      }
    }
  }
  size_t obase=(size_t)(b*64+co)*9216 + h*96 + wbase + pg*12;
  #pragma unroll
  for(int p=0;p<3;++p)
    *reinterpret_cast<float4*>(&c2[obase+p*4]) = *reinterpret_cast<float4*>(&acc[p*4]);
}

// merge: h[b,hw,c] = relu(bn2(c2) + bn_sc(res))  (NCHW -> token-major channel-last)
__global__ __launch_bounds__(256) void k_stem_merge(const float* __restrict__ c2,
    const float* __restrict__ res,
    const float* __restrict__ m2,const float* __restrict__ i2,
    const float* __restrict__ g2,const float* __restrict__ b2,
    const float* __restrict__ ms,const float* __restrict__ is,
    const float* __restrict__ gs,const float* __restrict__ bs,
    float* __restrict__ hOut){
  int idx=blockIdx.x*256+threadIdx.x; if(idx>=BSZ*64*9216)return;
  int c=idx&63; int hw=(idx>>6)%9216; int b=idx/(64*9216);
  size_t src=(size_t)(b*64+c)*9216+hw;
  float v=(c2[src]-m2[c])*i2[c]*g2[c]+b2[c];
  float r=(res[src]-ms[c])*is[c]*gs[c]+bs[c];
  hOut[idx]=fmaxf(v+r,0.f);
}

// ---------------- fused LayerNorm + GEMM (N=256, K=64) v2 ------------------
template<int OP>
__global__ __launch_bounds__(256) void k_ln_gemm(
    const float* __restrict__ A, const float* __restrict__ lng, const float* __restrict__ lnb,
    const float* __restrict__ W, const float* __restrict__ bias,
    float* __restrict__ out){
  __shared__ __align__(16) float Al[64*36];
  __shared__ __align__(16) float Pl[2][4*256];
  int tid = threadIdx.x;
  int j2 = tid & 127;
  int q  = tid >> 7;             // wave-uniform (waves 0,1 -> q=0; 2,3 -> q=1)
  int c0 = j2*2;
  float w0r[32], w1r[32];
  {
    const float* wp0 = W + (size_t)c0*64 + q*32;
    const float* wp1 = wp0 + 64;
    #pragma unroll
    for(int k4=0;k4<32;k4+=4){
      float4 a = *reinterpret_cast<const float4*>(wp0+k4);
      w0r[k4]=a.x; w0r[k4+1]=a.y; w0r[k4+2]=a.z; w0r[k4+3]=a.w;
      float4 b = *reinterpret_cast<const float4*>(wp1+k4);
      w1r[k4]=b.x; w1r[k4+1]=b.y; w1r[k4+2]=b.z; w1r[k4+3]=b.w;
    }
  }
  float bv0=0.f, bv1=0.f;
  if(OP==1){ bv0=bias[c0]; bv1=bias[c0+1]; }
  float gg = lng[tid&63], bbv = lnb[tid&63];
  int t0 = blockIdx.x*32;
  #pragma unroll
  for(int p=0;p<8;++p){
    int r = p*4 + (tid>>6);
    int c = tid&63;
    float v = A[(size_t)(t0+r)*64+c];
    float s=v, s2=v*v;
    #pragma unroll
    for(int off=32;off>0;off>>=1){ s+=__shfl_xor(s,off); s2+=__shfl_xor(s2,off); }
    float m=s*(1.f/64.f), var=s2*(1.f/64.f)-m*m;
    Al[c*36+r] = (v-m)*rsqrtf(var+1e-5f)*gg + bbv;
  }
  __syncthreads();
  const float* alk = Al + q*32*36;
  #pragma unroll 1
  for(int g=0;g<8;++g){
    float acc0[4], acc1[4];
    #pragma unroll
    for(int r=0;r<4;++r){ acc0[r]=0.f; acc1[r]=0.f; }
    const float* ap = alk + g*4;
    #pragma unroll 4
    for(int kk=0;kk<32;++kk){
      float4 a = *reinterpret_cast<const float4*>(ap + kk*36);
      float w0=w0r[kk], w1=w1r[kk];
      acc0[0]+=a.x*w0; acc0[1]+=a.y*w0; acc0[2]+=a.z*w0; acc0[3]+=a.w*w0;
      acc1[0]+=a.x*w1; acc1[1]+=a.y*w1; acc1[2]+=a.z*w1; acc1[3]+=a.w*w1;
    }
    float* pb = Pl[g&1];
    if(q==1){
      #pragma unroll
      for(int r=0;r<4;++r){
        float2 v2; v2.x=acc0[r]; v2.y=acc1[r];
        *reinterpret_cast<float2*>(&pb[r*256 + c0]) = v2;
      }
    }
    __syncthreads();
    if(q==0){
      #pragma unroll
      for(int r=0;r<4;++r){
        float2 pv = *reinterpret_cast<const float2*>(&pb[r*256 + c0]);
        float v0 = acc0[r] + pv.x + bv0;
        float v1 = acc1[r] + pv.y + bv1;
        if(OP==1){
          v0 = 0.5f*v0*(1.f+erff(v0*0.70710678118f));
          v1 = 0.5f*v1*(1.f+erff(v1*0.70710678118f));
        }
        int t = t0 + g*4 + r;
        float2 o; o.x=v0; o.y=v1;
        *reinterpret_cast<float2*>(&out[(size_t)t*256 + c0]) = o;
      }
    }
  }
}

// ---------------- GEMM N=64 (K=128/256) v2 --------------------------------
// Round-7 version was latency-bound: wave-uniform broadcast A loads from
// GLOBAL (16 useful B / ~200cy) + grid 384 (1.5 blk/CU) + 4 FMA/load.
// v2: 2 cols/thread (cp=tid&31) x 8-way k-split (q=tid>>5) -> 8 FMA per
// ds_read_b128; A tile (16 tokens) staged coalesced into LDS [r][q][KQ+4]
// (pad 4: 16B-aligned, half-wave broadcast addrs on disjoint banks);
// grid 1152 (16 tok/blk) -> ~4 resident blocks/CU hides LDS latency.
// 8 partials reduced via double-buffered Pl, 1 barrier per 4-token group.
template<int K>
__global__ __launch_bounds__(256) void k_gemm64(
    const float* __restrict__ A, const float* __restrict__ W,
    const float* __restrict__ bias, const float* __restrict__ res,
    float* __restrict__ out){
  constexpr int KQ  = K/8;          // 32 (K=256) / 16 (K=128)
  constexpr int KQP = KQ+4;         // padded slice stride
  __shared__ __align__(16) float Al[16*8*KQP];
  __shared__ __align__(16) float Pl[2][8*4*64];
  int tid = threadIdx.x;
  int cp = tid & 31;
  int q  = tid >> 5;
  int c0 = cp*2;
  float w0[KQ], w1[KQ];
  {
    const float* wp0 = W + (size_t)c0*K + q*KQ;
    const float* wp1 = wp0 + K;
    #pragma unroll
    for(int k4=0;k4<KQ;k4+=4){
      float4 a = *reinterpret_cast<const float4*>(wp0+k4);
      w0[k4]=a.x; w0[k4+1]=a.y; w0[k4+2]=a.z; w0[k4+3]=a.w;
      float4 b = *reinterpret_cast<const float4*>(wp1+k4);
      w1[k4]=b.x; w1[k4+1]=b.y; w1[k4+2]=b.z; w1[k4+3]=b.w;
    }
  }
  int t0 = blockIdx.x*16;
  // stage 16 rows of A (coalesced global float4 -> LDS [r][q][kk])
  constexpr int NL4 = (16*K)/(4*256);   // 4 (K=256) / 2 (K=128)
  #pragma unroll
  for(int i=0;i<NL4;++i){
    int e = i*256 + tid;
    int r = e / (K/4);
    int kq4 = e % (K/4);
    float4 v = *reinterpret_cast<const float4*>(A + (size_t)(t0+r)*K + kq4*4);
    int qq = (kq4*4)/KQ;
    int kk = (kq4*4)%KQ;
    *reinterpret_cast<float4*>(&Al[(r*8+qq)*KQP + kk]) = v;
  }
  __syncthreads();
  int rr = tid>>6, cc = tid&63;
  #pragma unroll 1
  for(int g=0;g<4;++g){
    float acc0[4], acc1[4];
    #pragma unroll
    for(int r=0;r<4;++r){ acc0[r]=0.f; acc1[r]=0.f; }
    #pragma unroll 1
    for(int k4=0;k4<KQ;k4+=4){
      #pragma unroll
      for(int r=0;r<4;++r){
        float4 a = *reinterpret_cast<const float4*>(&Al[((g*4+r)*8+q)*KQP + k4]);
        acc0[r] += a.x*w0[k4] + a.y*w0[k4+1] + a.z*w0[k4+2] + a.w*w0[k4+3];
        acc1[r] += a.x*w1[k4] + a.y*w1[k4+1] + a.z*w1[k4+2] + a.w*w1[k4+3];
      }
    }
    float* pb = Pl[g&1];
    #pragma unroll
    for(int r=0;r<4;++r){
      float2 v2; v2.x=acc0[r]; v2.y=acc1[r];
      *reinterpret_cast<float2*>(&pb[q*256 + r*64 + c0]) = v2;
    }
    __syncthreads();
    float v = 0.f;
    #pragma unroll
    for(int qq=0;qq<8;++qq) v += pb[qq*256 + rr*64 + cc];
    int t = t0 + g*4 + rr;
    if(bias) v += bias[cc];
    v += res[(size_t)t*64+cc];
    out[(size_t)t*64+cc] = v;
  }
}

// ---------------- depthwise causal conv (k=4) + silu ----------------
__global__ __launch_bounds__(256) void k_dwconv(const float* __restrict__ xz,
    const float* __restrict__ cw, const float* __restrict__ cb, float* __restrict__ xc){
  int idx=blockIdx.x*256+threadIdx.x; if(idx>=TTOK*128)return;
  int d=idx&127; int t=idx>>7;
  int b=t/LSEQ, l=t%LSEQ;
  float acc=cb[d];
  #pragma unroll
  for(int k=0;k<4;++k){
    int ls=l-3+k;
    if(ls>=0) acc += cw[d*4+k]*xz[(size_t)(b*LSEQ+ls)*256 + d];
  }
  xc[idx]=acc*sigmoidf_(acc);
}

// ---------------- x_proj GEMM (N=36,K=128) + fused delta ----------------
__global__ __launch_bounds__(256,2) void k_xproj_delta(
    const float* __restrict__ A, const float* __restrict__ W,
    const float* __restrict__ dtw, const float* __restrict__ dtb,
    float* __restrict__ dbl, float* __restrict__ delta, int tokensPerBlock){
  __shared__ __align__(16) float lds[37*128 + 56*128 + 56*4 + 512 + 128];
  float* Wl  = lds;               // [128][37] (pad 36->37: conflict-free)
  float* Al  = Wl + 37*128;       // [56][128]
  float* dtv = Al + 56*128;       // [56][4]
  float* dtwl= dtv + 56*4;        // [128][4]
  float* dtbl= dtwl + 512;        // [128]
  int tid=threadIdx.x;
  for(int i=tid;i<36*128;i+=256){int jj=i/128,kk=i%128; Wl[kk*37+jj]=W[i];}
  for(int i=tid;i<512;i+=256) dtwl[i]=dtw[i];
  if(tid<128) dtbl[tid]=dtb[tid];
  int j=tid%36, tg=tid/36;
  bool active = tg<7;
  int tStart=blockIdx.x*tokensPerBlock;
  for(int t0=tStart;t0<tStart+tokensPerBlock;t0+=56){
    __syncthreads();
    for(int i=tid;i<56*128;i+=256){
      int r=i>>7, kk=i&127; int t=t0+r;
      Al[i]=(t<TTOK)?A[(size_t)t*128+kk]:0.f;
    }
    __syncthreads();
    if(active){
      float acc[8];
      #pragma unroll
      for(int i=0;i<8;++i) acc[i]=0.f;
      const float* ar=Al+tg*8*128;
      for(int k=0;k<128;k+=4){
        float w0=Wl[k*37+j],w1=Wl[(k+1)*37+j],w2=Wl[(k+2)*37+j],w3=Wl[(k+3)*37+j];
        #pragma unroll
        for(int i=0;i<8;++i){
          float4 a=*reinterpret_cast<const float4*>(ar+i*128+k);
          acc[i]+=a.x*w0+a.y*w1+a.z*w2+a.w*w3;
        }
      }
      #pragma unroll
      for(int i=0;i<8;++i){
        int t=t0+tg*8+i;
        if(t<TTOK){
          dbl[(size_t)t*36+j]=acc[i];
          if(j<4) dtv[(tg*8+i)*4+j]=acc[i];
        }
      }
    }
    __syncthreads();
    for(int e=tid;e<56*128;e+=256){
      int r=e>>7, d=e&127; int t=t0+r;
      if(t<TTOK){
        float a0=dtv[r*4+0]*dtwl[d*4+0]+dtv[r*4+1]*dtwl[d*4+1]
                +dtv[r*4+2]*dtwl[d*4+2]+dtv[r*4+3]*dtwl[d*4+3]+dtbl[d];
        delta[(size_t)t*128+d]=fmaxf(a0,0.f)+log1pf(expf(-fabsf(a0)));
      }
    }
  }
}

// ---------------- scan phase 1 ----------------
__global__ __launch_bounds__(256) void k_scan1(const float* __restrict__ delta,
    const float* __restrict__ xc, const float* __restrict__ dbl,
    const float* __restrict__ A_log, float* __restrict__ chA, float* __restrict__ chH){
  int idx=blockIdx.x*256+threadIdx.x;
  int n=idx&15; int d=(idx>>4)&127; int chunk=(idx>>11)%NCH; int b=(idx>>11)/NCH;
  float a_const = -expf(A_log[d*16+n]);
  float aprod=1.f, h=0.f;
  int tBase = b*LSEQ + chunk*CS;
  for(int i=0;i<CS;++i){
    int t=tBase+i;
    float dl=delta[(size_t)t*128+d];
    float xv=xc[(size_t)t*128+d];
    float Bv=dbl[(size_t)t*36+4+n];
    float da=expf(dl*a_const);
    h = da*h + dl*xv*Bv;
    aprod *= da;
  }
  chA[idx]=aprod; chH[idx]=h;
}

// ---------------- scan phase 2 ----------------
__global__ __launch_bounds__(256) void k_scan2(const float* __restrict__ chA,
    const float* __restrict__ chH, float* __restrict__ chIn){
  int idx=blockIdx.x*256+threadIdx.x; if(idx>=BSZ*2048) return;
  int b=idx>>11; int dn=idx&2047;
  float H=0.f;
  for(int c=0;c<NCH;++c){
    size_t o=(size_t)(b*NCH+c)*2048+dn;
    chIn[o]=H;
    H = chA[o]*H + chH[o];
  }
}

// ---------------- scan phase 3 + fused gate ----------------
__global__ __launch_bounds__(256) void k_scan3(const float* __restrict__ delta,
    const float* __restrict__ xc, const float* __restrict__ dbl,
    const float* __restrict__ A_log, const float* __restrict__ chIn,
    const float* __restrict__ xz, const float* __restrict__ Dp,
    float* __restrict__ y){
  int tid=threadIdx.x;
  int gid = blockIdx.x*16 + (tid>>4);
  int n = tid&15;
  int d = gid%128; int chunk=(gid/128)%NCH; int b=gid/(128*NCH);
  float a_const = -expf(A_log[d*16+n]);
  float dpv = Dp[d];
  float h = chIn[(size_t)(b*NCH+chunk)*2048 + d*16+n];
  int tBase=b*LSEQ+chunk*CS;
  for(int i=0;i<CS;++i){
    int t=tBase+i;
    float dl=delta[(size_t)t*128+d];
    float xv=xc[(size_t)t*128+d];
    float Bv=dbl[(size_t)t*36+4+n];
    float Cv=dbl[(size_t)t*36+20+n];
    float da=expf(dl*a_const);
    h=da*h+dl*xv*Bv;
    float contrib=h*Cv;
    contrib += __shfl_xor(contrib,1);
    contrib += __shfl_xor(contrib,2);
    contrib += __shfl_xor(contrib,4);
    contrib += __shfl_xor(contrib,8);
    if(n==0){
      float z=xz[(size_t)t*256+128+d];
      y[(size_t)t*128+d]=(contrib + xv*dpv)*(z*sigmoidf_(z));
    }
  }
}

// ---------------- pool stage 1: 256 blocks of partials ----------------
__global__ __launch_bounds__(256) void k_pool1(const float* __restrict__ h,
    float* __restrict__ partial){
  int blk=blockIdx.x;            // b = blk>>7, slice s = blk&127 (72 px each)
  int b=blk>>7, s=blk&127;
  int tid=threadIdx.x; int c=tid&63, sl=tid>>6;
  float sum=0.f;
  int base = s*72;
  for(int p=sl;p<72;p+=4) sum += h[((size_t)b*9216 + base+p)*64 + c];
  __shared__ float ls[256];
  ls[tid]=sum; __syncthreads();
  if(sl==0) partial[(size_t)blk*64+c] = ls[c]+ls[64+c]+ls[128+c]+ls[192+c];
}

// ---------------- pool stage 2 + fc ----------------
__global__ __launch_bounds__(128) void k_pool2(const float* __restrict__ partial,
    const float* __restrict__ fcw, const float* __restrict__ fcb, float* __restrict__ out){
  int tid=threadIdx.x; int b=tid>>6, c=tid&63;
  float s=0.f;
  for(int k=0;k<128;++k) s += partial[(size_t)(b*128+k)*64+c];
  float v=(s/9216.f)*fcw[c];
  #pragma unroll
  for(int off=32;off>0;off>>=1) v+=__shfl_xor(v,off);
  if(c==0) out[b]=v+fcb[0];
}

extern "C" void kernel_launch(void* const* d_in, const int* in_sizes, int n_in,
                              void* d_out, int out_size, void* d_ws, size_t ws_size,
                              hipStream_t stream) {
  const float* x       = (const float*)d_in[0];
  const float* conv1_w = (const float*)d_in[1];
  const float* bn1_g   = (const float*)d_in[2];
  const float* bn1_b   = (const float*)d_in[3];
  const float* conv2_w = (const float*)d_in[4];
  const float* bn2_g   = (const float*)d_in[5];
  const float* bn2_b   = (const float*)d_in[6];
  const float* sc_w    = (const float*)d_in[7];
  const float* sc_g    = (const float*)d_in[8];
  const float* sc_b    = (const float*)d_in[9];
  const float* ln1_g   = (const float*)d_in[10];
  const float* ln1_b   = (const float*)d_in[11];
  const float* in_proj_w = (const float*)d_in[12];
  const float* conv_w  = (const float*)d_in[13];
  const float* conv_b  = (const float*)d_in[14];
  const float* x_proj_w= (const float*)d_in[15];
  const float* dt_w    = (const float*)d_in[16];
  const float* dt_b    = (const float*)d_in[17];
  const float* A_log   = (const float*)d_in[18];
  const float* Dp      = (const float*)d_in[19];
  const float* out_proj_w = (const float*)d_in[20];
  const float* ln2_g   = (const float*)d_in[21];
  const float* ln2_b   = (const float*)d_in[22];
  const float* mlp_w1  = (const float*)d_in[23];
  const float* mlp_b1  = (const float*)d_in[24];
  const float* mlp_w2  = (const float*)d_in[25];
  const float* mlp_b2  = (const float*)d_in[26];
  const float* fc_w    = (const float*)d_in[27];
  const float* fc_b    = (const float*)d_in[28];

  const size_t T = TTOK;
  float* ws    = (float*)d_ws;
  float* bufH  = ws;                  // T*64
  float* bufXZ = bufH  + 64*T;        // T*256 (also stem scratch)
  float* bufXC = bufXZ + 256*T;       // T*128
  float* bufDBL= bufXC + 128*T;       // T*36
  float* bufDLT= bufDBL+ 36*T;        // T*128
  float* bufY  = bufDLT+ 128*T;       // T*128
  float* chA   = bufY  + 128*T;       // B*NCH*2048
  float* chH   = chA   + BSZ*NCH*2048;
  float* chIn  = chH   + BSZ*NCH*2048;
  float* stats = chIn  + BSZ*NCH*2048; // 6*64
  float* partial = stats + 6*64;       // 256*64

  // stem scratch aliases inside bufXZ (each 2*64*9216 = 1179648 floats)
  float* c1   = bufXZ;
  float* c2   = bufXZ + 1179648;
  float* resb = bufXZ + 2*1179648;
  float *m1=stats, *i1=stats+64, *m2=stats+128, *i2=stats+192, *ms=stats+256, *is=stats+320;

  const int NE = BSZ*64*9216;
  const int gE = (NE+255)/256;

  k_stem_conv1<<<gE,256,0,stream>>>(x, conv1_w, sc_w, c1, resb);
  k_bnstats2<<<128,256,0,stream>>>(c1, resb, m1, i1, ms, is);
  k_bnrelu<<<gE,256,0,stream>>>(c1, m1, i1, bn1_g, bn1_b);
  k_stem_conv2<<<BSZ*96*2,256,0,stream>>>(c1, conv2_w, c2);
  k_bnstats<<<64,256,0,stream>>>(c2, m2, i2);
  k_stem_merge<<<gE,256,0,stream>>>(c2, resb, m2, i2, bn2_g, bn2_b, ms, is, sc_g, sc_b, bufH);

  const int gD = (int)((T*128+255)/256);
  for (int i=0;i<6;++i){
    const float* inw  = in_proj_w + (size_t)i*256*64;
    const float* cw   = conv_w    + (size_t)i*128*4;
    const float* cb   = conv_b    + (size_t)i*128;
    const float* xpw  = x_proj_w  + (size_t)i*36*128;
    const float* dtw  = dt_w      + (size_t)i*128*4;
    const float* dtb  = dt_b      + (size_t)i*128;
    const float* alog = A_log     + (size_t)i*128*16;
    const float* dp   = Dp        + (size_t)i*128;
    const float* opw  = out_proj_w+ (size_t)i*64*128;
    const float* w1   = mlp_w1    + (size_t)i*256*64;
    const float* b1   = mlp_b1    + (size_t)i*256;
    const float* w2   = mlp_w2    + (size_t)i*64*256;
    const float* b2   = mlp_b2    + (size_t)i*64;

    k_ln_gemm<0><<<576,256,0,stream>>>(bufH, ln1_g+i*64, ln1_b+i*64, inw, nullptr, bufXZ);
    k_dwconv<<<gD,256,0,stream>>>(bufXZ, cw, cb, bufXC);
    k_xproj_delta<<<330,256,0,stream>>>(bufXC, xpw, dtw, dtb, bufDBL, bufDLT, 56);
    k_scan1<<<BSZ*NCH*2048/256,256,0,stream>>>(bufDLT, bufXC, bufDBL, alog, chA, chH);
    k_scan2<<<(BSZ*2048+255)/256,256,0,stream>>>(chA, chH, chIn);
    k_scan3<<<BSZ*NCH*128/16,256,0,stream>>>(bufDLT, bufXC, bufDBL, alog, chIn, bufXZ, dp, bufY);
    k_gemm64<128><<<1152,256,0,stream>>>(bufY, opw, nullptr, bufH, bufH);
    k_ln_gemm<1><<<576,256,0,stream>>>(bufH, ln2_g+i*64, ln2_b+i*64, w1, b1, bufXZ);
    k_gemm64<256><<<1152,256,0,stream>>>(bufXZ, w2, b2, bufH, bufH);
  }

  k_pool1<<<256,256,0,stream>>>(bufH, partial);
  k_pool2<<<1,128,0,stream>>>(partial, fc_w, fc_b, (float*)d_out);
}

// Round 9
// 1689.676 us; speedup vs baseline: 2.2081x; 1.0771x over previous
//
#include <hip/hip_runtime.h>
#include <math.h>

// MambaNet forward: stem (conv/BN/relu) -> 6x [LN -> Mamba -> LN -> MLP] -> pool -> fc
// All f32. T = 18432 tokens (B=2, L=9216), d_model=64, d_inner=128, N_state=16.

#define TTOK 18432
#define LSEQ 9216
#define BSZ 2
#define CS 96     // scan chunk size
#define NCH 96    // number of chunks (CS*NCH == LSEQ)

__device__ __forceinline__ float sigmoidf_(float x){ return 1.f/(1.f+expf(-x)); }

// ---------------- Stem ----------------
__global__ __launch_bounds__(256) void k_stem_conv1(const float* __restrict__ x,
    const float* __restrict__ w1, const float* __restrict__ scw,
    float* __restrict__ c1, float* __restrict__ res){
  int idx = blockIdx.x*256 + threadIdx.x;
  if (idx >= BSZ*64*9216) return;
  int hw = idx % 9216; int c = (idx/9216) & 63; int b = idx/(9216*64);
  int h = hw/96, w = hw%96;
  const float* xb = x + b*9216;
  float acc = 0.f;
  for (int dh=-1; dh<=1; ++dh){
    int hh=h+dh; if(hh<0||hh>=96) continue;
    for (int dw=-1; dw<=1; ++dw){
      int ww=w+dw; if(ww<0||ww>=96) continue;
      acc += xb[hh*96+ww]*w1[c*9+(dh+1)*3+(dw+1)];
    }
  }
  c1[idx]=acc;
  res[idx]=xb[hw]*scw[c];
}

// per-channel batch stats for TWO tensors in one launch (128 blocks)
__global__ __launch_bounds__(256) void k_bnstats2(const float* __restrict__ srcA,
    const float* __restrict__ srcB,
    float* __restrict__ meanA, float* __restrict__ istdA,
    float* __restrict__ meanB, float* __restrict__ istdB){
  int c = blockIdx.x & 63; int tid = threadIdx.x;
  const float* src = (blockIdx.x < 64)? srcA : srcB;
  float* mean = (blockIdx.x < 64)? meanA : meanB;
  float* istd = (blockIdx.x < 64)? istdA : istdB;
  float s=0.f, s2=0.f;
  for (int b=0;b<BSZ;++b){
    const float* p = src + (size_t)(b*64+c)*9216;
    for (int i=tid;i<9216;i+=256){ float v=p[i]; s+=v; s2+=v*v; }
  }
  __shared__ float ls[256], ls2[256];
  ls[tid]=s; ls2[tid]=s2; __syncthreads();
  for(int off=128;off>0;off>>=1){
    if(tid<off){ ls[tid]+=ls[tid+off]; ls2[tid]+=ls2[tid+off]; }
    __syncthreads();
  }
  if(tid==0){
    float m=ls[0]/18432.f; float v=ls2[0]/18432.f - m*m;
    mean[c]=m; istd[c]=rsqrtf(v+1e-5f);
  }
}

__global__ __launch_bounds__(256) void k_bnstats(const float* __restrict__ src,
    float* __restrict__ mean, float* __restrict__ istd){
  int c = blockIdx.x; int tid = threadIdx.x;
  float s=0.f, s2=0.f;
  for (int b=0;b<BSZ;++b){
    const float* p = src + (size_t)(b*64+c)*9216;
    for (int i=tid;i<9216;i+=256){ float v=p[i]; s+=v; s2+=v*v; }
  }
  __shared__ float ls[256], ls2[256];
  ls[tid]=s; ls2[tid]=s2; __syncthreads();
  for(int off=128;off>0;off>>=1){
    if(tid<off){ ls[tid]+=ls[tid+off]; ls2[tid]+=ls2[tid+off]; }
    __syncthreads();
  }
  if(tid==0){
    float m=ls[0]/18432.f; float v=ls2[0]/18432.f - m*m;
    mean[c]=m; istd[c]=rsqrtf(v+1e-5f);
  }
}

__global__ __launch_bounds__(256) void k_bnrelu(float* __restrict__ t,
    const float* __restrict__ mean, const float* __restrict__ istd,
    const float* __restrict__ g, const float* __restrict__ bb){
  int idx = blockIdx.x*256+threadIdx.x; if(idx>=BSZ*64*9216) return;
  int c=(idx/9216)&63;
  float v=(t[idx]-mean[c])*istd[c]*g[c]+bb[c];
  t[idx]=fmaxf(v,0.f);
}

// Tiled direct conv 64->64, 3x3. Block = (b, out-row h, half-row wh).
__global__ __launch_bounds__(256) void k_stem_conv2(const float* __restrict__ h1,
    const float* __restrict__ w2, float* __restrict__ c2){
  __shared__ __align__(16) float in_lds[16*156];   // [ci][3][52]
  __shared__ float w_lds[64*145];                  // [co][16*9 (+1 pad)]
  int blk=blockIdx.x;
  int wh=blk&1, h=(blk>>1)%96, b=blk/(2*96);
  int tid=threadIdx.x;
  int co=tid&63, pg=tid>>6;
  float acc[12];
  #pragma unroll
  for(int i=0;i<12;++i) acc[i]=0.f;
  int wbase = wh*48;
  const float* hb = h1 + (size_t)b*64*9216;
  for(int cc=0;cc<4;++cc){
    __syncthreads();
    for(int e=tid;e<16*3*50;e+=256){
      int ci=e/150, rr=e%150; int tr=rr/50, wl=rr%50;
      int hh=h+tr-1, ww=wbase+wl-1;
      float v=0.f;
      if(hh>=0&&hh<96&&ww>=0&&ww<96) v=hb[(size_t)(cc*16+ci)*9216 + hh*96+ww];
      in_lds[ci*156 + tr*52 + wl]=v;
    }
    for(int e=tid;e<64*144;e+=256){
      int c_=e/144, r=e%144;
      w_lds[c_*145+r]=w2[(size_t)c_*576 + cc*144 + r];
    }
    __syncthreads();
    for(int ci=0;ci<16;++ci){
      float wr[9];
      #pragma unroll
      for(int t=0;t<9;++t) wr[t]=w_lds[co*145+ci*9+t];
      const float* ibase = in_lds + ci*156;
      #pragma unroll
      for(int tr=0;tr<3;++tr){
        const float* row = ibase + tr*52 + pg*12;
        float win[14];
        #pragma unroll
        for(int q=0;q<14;++q) win[q]=row[q];
        #pragma unroll
        for(int p=0;p<12;++p)
          acc[p] += win[p]*wr[tr*3+0] + win[p+1]*wr[tr*3+1] + win[p+2]*wr[tr*3+2];
      }
    }
  }
  size_t obase=(size_t)(b*64+co)*9216 + h*96 + wbase + pg*12;
  #pragma unroll
  for(int p=0;p<3;++p)
    *reinterpret_cast<float4*>(&c2[obase+p*4]) = *reinterpret_cast<float4*>(&acc[p*4]);
}

// merge: h[b,hw,c] = relu(bn2(c2) + bn_sc(res))  (NCHW -> token-major channel-last)
__global__ __launch_bounds__(256) void k_stem_merge(const float* __restrict__ c2,
    const float* __restrict__ res,
    const float* __restrict__ m2,const float* __restrict__ i2,
    const float* __restrict__ g2,const float* __restrict__ b2,
    const float* __restrict__ ms,const float* __restrict__ is,
    const float* __restrict__ gs,const float* __restrict__ bs,
    float* __restrict__ hOut){
  int idx=blockIdx.x*256+threadIdx.x; if(idx>=BSZ*64*9216)return;
  int c=idx&63; int hw=(idx>>6)%9216; int b=idx/(64*9216);
  size_t src=(size_t)(b*64+c)*9216+hw;
  float v=(c2[src]-m2[c])*i2[c]*g2[c]+b2[c];
  float r=(res[src]-ms[c])*is[c]*gs[c]+bs[c];
  hOut[idx]=fmaxf(v+r,0.f);
}

// ---------------- fused LayerNorm + GEMM (N=256, K=64) v2 ------------------
template<int OP>
__global__ __launch_bounds__(256) void k_ln_gemm(
    const float* __restrict__ A, const float* __restrict__ lng, const float* __restrict__ lnb,
    const float* __restrict__ W, const float* __restrict__ bias,
    float* __restrict__ out){
  __shared__ __align__(16) float Al[64*36];
  __shared__ __align__(16) float Pl[2][4*256];
  int tid = threadIdx.x;
  int j2 = tid & 127;
  int q  = tid >> 7;             // wave-uniform (waves 0,1 -> q=0; 2,3 -> q=1)
  int c0 = j2*2;
  float w0r[32], w1r[32];
  {
    const float* wp0 = W + (size_t)c0*64 + q*32;
    const float* wp1 = wp0 + 64;
    #pragma unroll
    for(int k4=0;k4<32;k4+=4){
      float4 a = *reinterpret_cast<const float4*>(wp0+k4);
      w0r[k4]=a.x; w0r[k4+1]=a.y; w0r[k4+2]=a.z; w0r[k4+3]=a.w;
      float4 b = *reinterpret_cast<const float4*>(wp1+k4);
      w1r[k4]=b.x; w1r[k4+1]=b.y; w1r[k4+2]=b.z; w1r[k4+3]=b.w;
    }
  }
  float bv0=0.f, bv1=0.f;
  if(OP==1){ bv0=bias[c0]; bv1=bias[c0+1]; }
  float gg = lng[tid&63], bbv = lnb[tid&63];
  int t0 = blockIdx.x*32;
  #pragma unroll
  for(int p=0;p<8;++p){
    int r = p*4 + (tid>>6);
    int c = tid&63;
    float v = A[(size_t)(t0+r)*64+c];
    float s=v, s2=v*v;
    #pragma unroll
    for(int off=32;off>0;off>>=1){ s+=__shfl_xor(s,off); s2+=__shfl_xor(s2,off); }
    float m=s*(1.f/64.f), var=s2*(1.f/64.f)-m*m;
    Al[c*36+r] = (v-m)*rsqrtf(var+1e-5f)*gg + bbv;
  }
  __syncthreads();
  const float* alk = Al + q*32*36;
  #pragma unroll 1
  for(int g=0;g<8;++g){
    float acc0[4], acc1[4];
    #pragma unroll
    for(int r=0;r<4;++r){ acc0[r]=0.f; acc1[r]=0.f; }
    const float* ap = alk + g*4;
    #pragma unroll 4
    for(int kk=0;kk<32;++kk){
      float4 a = *reinterpret_cast<const float4*>(ap + kk*36);
      float w0=w0r[kk], w1=w1r[kk];
      acc0[0]+=a.x*w0; acc0[1]+=a.y*w0; acc0[2]+=a.z*w0; acc0[3]+=a.w*w0;
      acc1[0]+=a.x*w1; acc1[1]+=a.y*w1; acc1[2]+=a.z*w1; acc1[3]+=a.w*w1;
    }
    float* pb = Pl[g&1];
    if(q==1){
      #pragma unroll
      for(int r=0;r<4;++r){
        float2 v2; v2.x=acc0[r]; v2.y=acc1[r];
        *reinterpret_cast<float2*>(&pb[r*256 + c0]) = v2;
      }
    }
    __syncthreads();
    if(q==0){
      #pragma unroll
      for(int r=0;r<4;++r){
        float2 pv = *reinterpret_cast<const float2*>(&pb[r*256 + c0]);
        float v0 = acc0[r] + pv.x + bv0;
        float v1 = acc1[r] + pv.y + bv1;
        if(OP==1){
          v0 = 0.5f*v0*(1.f+erff(v0*0.70710678118f));
          v1 = 0.5f*v1*(1.f+erff(v1*0.70710678118f));
        }
        int t = t0 + g*4 + r;
        float2 o; o.x=v0; o.y=v1;
        *reinterpret_cast<float2*>(&out[(size_t)t*256 + c0]) = o;
      }
    }
  }
}

// ---------------- GEMM N=64 (K=128/256) v2 --------------------------------
template<int K>
__global__ __launch_bounds__(256) void k_gemm64(
    const float* __restrict__ A, const float* __restrict__ W,
    const float* __restrict__ bias, const float* __restrict__ res,
    float* __restrict__ out){
  constexpr int KQ  = K/8;          // 32 (K=256) / 16 (K=128)
  constexpr int KQP = KQ+4;         // padded slice stride
  __shared__ __align__(16) float Al[16*8*KQP];
  __shared__ __align__(16) float Pl[2][8*4*64];
  int tid = threadIdx.x;
  int cp = tid & 31;
  int q  = tid >> 5;
  int c0 = cp*2;
  float w0[KQ], w1[KQ];
  {
    const float* wp0 = W + (size_t)c0*K + q*KQ;
    const float* wp1 = wp0 + K;
    #pragma unroll
    for(int k4=0;k4<KQ;k4+=4){
      float4 a = *reinterpret_cast<const float4*>(wp0+k4);
      w0[k4]=a.x; w0[k4+1]=a.y; w0[k4+2]=a.z; w0[k4+3]=a.w;
      float4 b = *reinterpret_cast<const float4*>(wp1+k4);
      w1[k4]=b.x; w1[k4+1]=b.y; w1[k4+2]=b.z; w1[k4+3]=b.w;
    }
  }
  int t0 = blockIdx.x*16;
  constexpr int NL4 = (16*K)/(4*256);   // 4 (K=256) / 2 (K=128)
  #pragma unroll
  for(int i=0;i<NL4;++i){
    int e = i*256 + tid;
    int r = e / (K/4);
    int kq4 = e % (K/4);
    float4 v = *reinterpret_cast<const float4*>(A + (size_t)(t0+r)*K + kq4*4);
    int qq = (kq4*4)/KQ;
    int kk = (kq4*4)%KQ;
    *reinterpret_cast<float4*>(&Al[(r*8+qq)*KQP + kk]) = v;
  }
  __syncthreads();
  int rr = tid>>6, cc = tid&63;
  #pragma unroll 1
  for(int g=0;g<4;++g){
    float acc0[4], acc1[4];
    #pragma unroll
    for(int r=0;r<4;++r){ acc0[r]=0.f; acc1[r]=0.f; }
    #pragma unroll 1
    for(int k4=0;k4<KQ;k4+=4){
      #pragma unroll
      for(int r=0;r<4;++r){
        float4 a = *reinterpret_cast<const float4*>(&Al[((g*4+r)*8+q)*KQP + k4]);
        acc0[r] += a.x*w0[k4] + a.y*w0[k4+1] + a.z*w0[k4+2] + a.w*w0[k4+3];
        acc1[r] += a.x*w1[k4] + a.y*w1[k4+1] + a.z*w1[k4+2] + a.w*w1[k4+3];
      }
    }
    float* pb = Pl[g&1];
    #pragma unroll
    for(int r=0;r<4;++r){
      float2 v2; v2.x=acc0[r]; v2.y=acc1[r];
      *reinterpret_cast<float2*>(&pb[q*256 + r*64 + c0]) = v2;
    }
    __syncthreads();
    float v = 0.f;
    #pragma unroll
    for(int qq=0;qq<8;++qq) v += pb[qq*256 + rr*64 + cc];
    int t = t0 + g*4 + rr;
    if(bias) v += bias[cc];
    v += res[(size_t)t*64+cc];
    out[(size_t)t*64+cc] = v;
  }
}

// ---------------- depthwise causal conv (k=4) + silu ----------------
__global__ __launch_bounds__(256) void k_dwconv(const float* __restrict__ xz,
    const float* __restrict__ cw, const float* __restrict__ cb, float* __restrict__ xc){
  int idx=blockIdx.x*256+threadIdx.x; if(idx>=TTOK*128)return;
  int d=idx&127; int t=idx>>7;
  int b=t/LSEQ, l=t%LSEQ;
  float acc=cb[d];
  #pragma unroll
  for(int k=0;k<4;++k){
    int ls=l-3+k;
    if(ls>=0) acc += cw[d*4+k]*xz[(size_t)(b*LSEQ+ls)*256 + d];
  }
  xc[idx]=acc*sigmoidf_(acc);
}

// ---------------- x_proj GEMM (N=36,K=128) + fused delta ----------------
__global__ __launch_bounds__(256,2) void k_xproj_delta(
    const float* __restrict__ A, const float* __restrict__ W,
    const float* __restrict__ dtw, const float* __restrict__ dtb,
    float* __restrict__ dbl, float* __restrict__ delta, int tokensPerBlock){
  __shared__ __align__(16) float lds[37*128 + 56*128 + 56*4 + 512 + 128];
  float* Wl  = lds;               // [128][37] (pad 36->37: conflict-free)
  float* Al  = Wl + 37*128;       // [56][128]
  float* dtv = Al + 56*128;       // [56][4]
  float* dtwl= dtv + 56*4;        // [128][4]
  float* dtbl= dtwl + 512;        // [128]
  int tid=threadIdx.x;
  for(int i=tid;i<36*128;i+=256){int jj=i/128,kk=i%128; Wl[kk*37+jj]=W[i];}
  for(int i=tid;i<512;i+=256) dtwl[i]=dtw[i];
  if(tid<128) dtbl[tid]=dtb[tid];
  int j=tid%36, tg=tid/36;
  bool active = tg<7;
  int tStart=blockIdx.x*tokensPerBlock;
  for(int t0=tStart;t0<tStart+tokensPerBlock;t0+=56){
    __syncthreads();
    for(int i=tid;i<56*128;i+=256){
      int r=i>>7, kk=i&127; int t=t0+r;
      Al[i]=(t<TTOK)?A[(size_t)t*128+kk]:0.f;
    }
    __syncthreads();
    if(active){
      float acc[8];
      #pragma unroll
      for(int i=0;i<8;++i) acc[i]=0.f;
      const float* ar=Al+tg*8*128;
      for(int k=0;k<128;k+=4){
        float w0=Wl[k*37+j],w1=Wl[(k+1)*37+j],w2=Wl[(k+2)*37+j],w3=Wl[(k+3)*37+j];
        #pragma unroll
        for(int i=0;i<8;++i){
          float4 a=*reinterpret_cast<const float4*>(ar+i*128+k);
          acc[i]+=a.x*w0+a.y*w1+a.z*w2+a.w*w3;
        }
      }
      #pragma unroll
      for(int i=0;i<8;++i){
        int t=t0+tg*8+i;
        if(t<TTOK){
          dbl[(size_t)t*36+j]=acc[i];
          if(j<4) dtv[(tg*8+i)*4+j]=acc[i];
        }
      }
    }
    __syncthreads();
    for(int e=tid;e<56*128;e+=256){
      int r=e>>7, d=e&127; int t=t0+r;
      if(t<TTOK){
        float a0=dtv[r*4+0]*dtwl[d*4+0]+dtv[r*4+1]*dtwl[d*4+1]
                +dtv[r*4+2]*dtwl[d*4+2]+dtv[r*4+3]*dtwl[d*4+3]+dtbl[d];
        delta[(size_t)t*128+d]=fmaxf(a0,0.f)+log1pf(expf(-fabsf(a0)));
      }
    }
  }
}

// ---------------- scan phase 1 v2: 2 states/lane, 8 lanes/d ----------------
// Wave covers 8 d (2x amortization of dl/xv broadcast + addressing); B as
// aligned float2; __expf (v_exp) replaces libm expf in the hot loop; pointers
// hand-hoisted with constant increments. grid 768 x 256.
__global__ __launch_bounds__(256) void k_scan1(const float* __restrict__ delta,
    const float* __restrict__ xc, const float* __restrict__ dbl,
    const float* __restrict__ A_log, float* __restrict__ chA, float* __restrict__ chH){
  int tid=threadIdx.x;
  int gid = blockIdx.x*32 + (tid>>3);   // over B*NCH*128 d-groups
  int n0 = (tid&7)*2;
  int d = gid & 127; int chunk = (gid>>7)%NCH; int b = gid/(128*NCH);
  float ac0 = -expf(A_log[d*16+n0]);
  float ac1 = -expf(A_log[d*16+n0+1]);
  int tBase = b*LSEQ + chunk*CS;
  const float* pd = delta + (size_t)tBase*128 + d;
  const float* px = xc    + (size_t)tBase*128 + d;
  const float* pb = dbl   + (size_t)tBase*36 + 4 + n0;
  float a0=1.f, a1=1.f, h0=0.f, h1=0.f;
  #pragma unroll 4
  for(int i=0;i<CS;++i){
    float dl=*pd, xv=*px;
    float2 Bv=*reinterpret_cast<const float2*>(pb);
    float da0=__expf(dl*ac0), da1=__expf(dl*ac1);
    float du=dl*xv;
    h0=da0*h0+du*Bv.x; h1=da1*h1+du*Bv.y;
    a0*=da0; a1*=da1;
    pd+=128; px+=128; pb+=36;
  }
  size_t o=(size_t)(b*NCH+chunk)*2048 + d*16 + n0;
  float2 av; av.x=a0; av.y=a1; *reinterpret_cast<float2*>(&chA[o])=av;
  float2 hv; hv.x=h0; hv.y=h1; *reinterpret_cast<float2*>(&chH[o])=hv;
}

// ---------------- scan phase 2 ----------------
__global__ __launch_bounds__(256) void k_scan2(const float* __restrict__ chA,
    const float* __restrict__ chH, float* __restrict__ chIn){
  int idx=blockIdx.x*256+threadIdx.x; if(idx>=BSZ*2048) return;
  int b=idx>>11; int dn=idx&2047;
  float H=0.f;
  for(int c=0;c<NCH;++c){
    size_t o=(size_t)(b*NCH+c)*2048+dn;
    chIn[o]=H;
    H = chA[o]*H + chH[o];
  }
}

// ---------------- scan phase 3 v2 + fused gate ------------------------------
// 2 states/lane, 8 lanes/d; B/C float2; 3-step shfl reduce (was 4);
// __expf; hoisted pointers. Lane n2==0 of each 8-lane group emits y.
__global__ __launch_bounds__(256) void k_scan3(const float* __restrict__ delta,
    const float* __restrict__ xc, const float* __restrict__ dbl,
    const float* __restrict__ A_log, const float* __restrict__ chIn,
    const float* __restrict__ xz, const float* __restrict__ Dp,
    float* __restrict__ y){
  int tid=threadIdx.x;
  int gid = blockIdx.x*32 + (tid>>3);
  int n2 = tid&7; int n0 = n2*2;
  int d = gid & 127; int chunk=(gid>>7)%NCH; int b=gid/(128*NCH);
  float ac0 = -expf(A_log[d*16+n0]);
  float ac1 = -expf(A_log[d*16+n0+1]);
  float dpv = Dp[d];
  size_t o=(size_t)(b*NCH+chunk)*2048 + d*16 + n0;
  float2 hin=*reinterpret_cast<const float2*>(&chIn[o]);
  float h0=hin.x, h1=hin.y;
  int tBase=b*LSEQ+chunk*CS;
  const float* pd = delta + (size_t)tBase*128 + d;
  const float* px = xc    + (size_t)tBase*128 + d;
  const float* pb = dbl   + (size_t)tBase*36 + 4 + n0;
  const float* pc = dbl   + (size_t)tBase*36 + 20 + n0;
  const float* pz = xz    + (size_t)tBase*256 + 128 + d;
  float* py = y + (size_t)tBase*128 + d;
  #pragma unroll 2
  for(int i=0;i<CS;++i){
    float dl=*pd, xv=*px;
    float2 Bv=*reinterpret_cast<const float2*>(pb);
    float2 Cv=*reinterpret_cast<const float2*>(pc);
    float da0=__expf(dl*ac0), da1=__expf(dl*ac1);
    float du=dl*xv;
    h0=da0*h0+du*Bv.x; h1=da1*h1+du*Bv.y;
    float contrib = h0*Cv.x + h1*Cv.y;
    contrib += __shfl_xor(contrib,1);
    contrib += __shfl_xor(contrib,2);
    contrib += __shfl_xor(contrib,4);
    if(n2==0){
      float z=*pz;
      float sg = z/(1.f+__expf(-z));
      *py = (contrib + xv*dpv)*sg;
    }
    pd+=128; px+=128; pb+=36; pc+=36; pz+=256; py+=128;
  }
}

// ---------------- pool stage 1: 256 blocks of partials ----------------
__global__ __launch_bounds__(256) void k_pool1(const float* __restrict__ h,
    float* __restrict__ partial){
  int blk=blockIdx.x;            // b = blk>>7, slice s = blk&127 (72 px each)
  int b=blk>>7, s=blk&127;
  int tid=threadIdx.x; int c=tid&63, sl=tid>>6;
  float sum=0.f;
  int base = s*72;
  for(int p=sl;p<72;p+=4) sum += h[((size_t)b*9216 + base+p)*64 + c];
  __shared__ float ls[256];
  ls[tid]=sum; __syncthreads();
  if(sl==0) partial[(size_t)blk*64+c] = ls[c]+ls[64+c]+ls[128+c]+ls[192+c];
}

// ---------------- pool stage 2 + fc ----------------
__global__ __launch_bounds__(128) void k_pool2(const float* __restrict__ partial,
    const float* __restrict__ fcw, const float* __restrict__ fcb, float* __restrict__ out){
  int tid=threadIdx.x; int b=tid>>6, c=tid&63;
  float s=0.f;
  for(int k=0;k<128;++k) s += partial[(size_t)(b*128+k)*64+c];
  float v=(s/9216.f)*fcw[c];
  #pragma unroll
  for(int off=32;off>0;off>>=1) v+=__shfl_xor(v,off);
  if(c==0) out[b]=v+fcb[0];
}

extern "C" void kernel_launch(void* const* d_in, const int* in_sizes, int n_in,
                              void* d_out, int out_size, void* d_ws, size_t ws_size,
                              hipStream_t stream) {
  const float* x       = (const float*)d_in[0];
  const float* conv1_w = (const float*)d_in[1];
  const float* bn1_g   = (const float*)d_in[2];
  const float* bn1_b   = (const float*)d_in[3];
  const float* conv2_w = (const float*)d_in[4];
  const float* bn2_g   = (const float*)d_in[5];
  const float* bn2_b   = (const float*)d_in[6];
  const float* sc_w    = (const float*)d_in[7];
  const float* sc_g    = (const float*)d_in[8];
  const float* sc_b    = (const float*)d_in[9];
  const float* ln1_g   = (const float*)d_in[10];
  const float* ln1_b   = (const float*)d_in[11];
  const float* in_proj_w = (const float*)d_in[12];
  const float* conv_w  = (const float*)d_in[13];
  const float* conv_b  = (const float*)d_in[14];
  const float* x_proj_w= (const float*)d_in[15];
  const float* dt_w    = (const float*)d_in[16];
  const float* dt_b    = (const float*)d_in[17];
  const float* A_log   = (const float*)d_in[18];
  const float* Dp      = (const float*)d_in[19];
  const float* out_proj_w = (const float*)d_in[20];
  const float* ln2_g   = (const float*)d_in[21];
  const float* ln2_b   = (const float*)d_in[22];
  const float* mlp_w1  = (const float*)d_in[23];
  const float* mlp_b1  = (const float*)d_in[24];
  const float* mlp_w2  = (const float*)d_in[25];
  const float* mlp_b2  = (const float*)d_in[26];
  const float* fc_w    = (const float*)d_in[27];
  const float* fc_b    = (const float*)d_in[28];

  const size_t T = TTOK;
  float* ws    = (float*)d_ws;
  float* bufH  = ws;                  // T*64
  float* bufXZ = bufH  + 64*T;        // T*256 (also stem scratch)
  float* bufXC = bufXZ + 256*T;       // T*128
  float* bufDBL= bufXC + 128*T;       // T*36
  float* bufDLT= bufDBL+ 36*T;        // T*128
  float* bufY  = bufDLT+ 128*T;       // T*128
  float* chA   = bufY  + 128*T;       // B*NCH*2048
  float* chH   = chA   + BSZ*NCH*2048;
  float* chIn  = chH   + BSZ*NCH*2048;
  float* stats = chIn  + BSZ*NCH*2048; // 6*64
  float* partial = stats + 6*64;       // 256*64

  // stem scratch aliases inside bufXZ (each 2*64*9216 = 1179648 floats)
  float* c1   = bufXZ;
  float* c2   = bufXZ + 1179648;
  float* resb = bufXZ + 2*1179648;
  float *m1=stats, *i1=stats+64, *m2=stats+128, *i2=stats+192, *ms=stats+256, *is=stats+320;

  const int NE = BSZ*64*9216;
  const int gE = (NE+255)/256;

  k_stem_conv1<<<gE,256,0,stream>>>(x, conv1_w, sc_w, c1, resb);
  k_bnstats2<<<128,256,0,stream>>>(c1, resb, m1, i1, ms, is);
  k_bnrelu<<<gE,256,0,stream>>>(c1, m1, i1, bn1_g, bn1_b);
  k_stem_conv2<<<BSZ*96*2,256,0,stream>>>(c1, conv2_w, c2);
  k_bnstats<<<64,256,0,stream>>>(c2, m2, i2);
  k_stem_merge<<<gE,256,0,stream>>>(c2, resb, m2, i2, bn2_g, bn2_b, ms, is, sc_g, sc_b, bufH);

  const int gD = (int)((T*128+255)/256);
  for (int i=0;i<6;++i){
    const float* inw  = in_proj_w + (size_t)i*256*64;
    const float* cw   = conv_w    + (size_t)i*128*4;
    const float* cb   = conv_b    + (size_t)i*128;
    const float* xpw  = x_proj_w  + (size_t)i*36*128;
    const float* dtw  = dt_w      + (size_t)i*128*4;
    const float* dtb  = dt_b      + (size_t)i*128;
    const float* alog = A_log     + (size_t)i*128*16;
    const float* dp   = Dp        + (size_t)i*128;
    const float* opw  = out_proj_w+ (size_t)i*64*128;
    const float* w1   = mlp_w1    + (size_t)i*256*64;
    const float* b1   = mlp_b1    + (size_t)i*256;
    const float* w2   = mlp_w2    + (size_t)i*64*256;
    const float* b2   = mlp_b2    + (size_t)i*64;

    k_ln_gemm<0><<<576,256,0,stream>>>(bufH, ln1_g+i*64, ln1_b+i*64, inw, nullptr, bufXZ);
    k_dwconv<<<gD,256,0,stream>>>(bufXZ, cw, cb, bufXC);
    k_xproj_delta<<<330,256,0,stream>>>(bufXC, xpw, dtw, dtb, bufDBL, bufDLT, 56);
    k_scan1<<<768,256,0,stream>>>(bufDLT, bufXC, bufDBL, alog, chA, chH);
    k_scan2<<<(BSZ*2048+255)/256,256,0,stream>>>(chA, chH, chIn);
    k_scan3<<<768,256,0,stream>>>(bufDLT, bufXC, bufDBL, alog, chIn, bufXZ, dp, bufY);
    k_gemm64<128><<<1152,256,0,stream>>>(bufY, opw, nullptr, bufH, bufH);
    k_ln_gemm<1><<<576,256,0,stream>>>(bufH, ln2_g+i*64, ln2_b+i*64, w1, b1, bufXZ);
    k_gemm64<256><<<1152,256,0,stream>>>(bufXZ, w2, b2, bufH, bufH);
  }

  k_pool1<<<256,256,0,stream>>>(bufH, partial);
  k_pool2<<<1,128,0,stream>>>(partial, fc_w, fc_b, (float*)d_out);
}